// Round 6
// baseline (609.656 us; speedup 1.0000x reference)
//
#include <hip/hip_runtime.h>
#include <math.h>

#define GN 400
#define NPER 50
#define NN 20000
#define LL 4

typedef __attribute__((ext_vector_type(8))) short short8;
typedef __attribute__((ext_vector_type(4))) float f32x4;

__device__ __forceinline__ float fast_rcp(float x) {
#if __has_builtin(__builtin_amdgcn_rcpf)
  return __builtin_amdgcn_rcpf(x);
#else
  return 1.0f / x;
#endif
}
__device__ __forceinline__ float silu_f(float x) {
  return x * fast_rcp(1.0f + __expf(-x));
}
// Exact RNE (weights only)
__device__ __forceinline__ unsigned short f2bu(float f) {
  unsigned int u = __float_as_uint(f);
  unsigned int r = (u + 0x7fffu + ((u >> 16) & 1u)) >> 16;
  return (unsigned short)r;
}
// Fast round-half-up pack: 2 adds + 1 v_perm
__device__ __forceinline__ unsigned int pack2bf(float lo, float hi) {
  unsigned int a = __float_as_uint(lo) + 0x8000u;
  unsigned int b = __float_as_uint(hi) + 0x8000u;
#if __has_builtin(__builtin_amdgcn_perm)
  return __builtin_amdgcn_perm(b, a, 0x07060302);
#else
  return (b & 0xffff0000u) | (a >> 16);
#endif
}
__device__ __forceinline__ float bhi(unsigned int u) { return __uint_as_float(u & 0xffff0000u); }
__device__ __forceinline__ float blo(unsigned int u) { return __uint_as_float(u << 16); }

__device__ __forceinline__ short8 pack8(const float* v) {
  union { unsigned int u[4]; short8 s; } t;
  t.u[0] = pack2bf(v[0], v[1]);
  t.u[1] = pack2bf(v[2], v[3]);
  t.u[2] = pack2bf(v[4], v[5]);
  t.u[3] = pack2bf(v[6], v[7]);
  return t.s;
}

// ---------------------------------------------------------------------------
// Time embedding MLP + per-layer per-graph t-projections (400 graphs)
// ---------------------------------------------------------------------------
__global__ __launch_bounds__(128) void time_kernel(
    const float* __restrict__ t,
    const float* __restrict__ tm_W1, const float* __restrict__ tm_b1,
    const float* __restrict__ tm_W2, const float* __restrict__ tm_b2,
    const float* __restrict__ eW1, const float* __restrict__ eb1,
    const float* __restrict__ nW1, const float* __restrict__ nb1,
    float* __restrict__ temb, float* __restrict__ tE, float* __restrict__ tN)
{
  int g = blockIdx.x;
  int j = threadIdx.x;
  __shared__ float x[128];
  __shared__ float hid[256];
  __shared__ float te[128];
  float tv = t[g];
  if (j < 64) {
    float f = __expf((float)j * (-9.210340371976184f / 63.0f));
    float a = tv * f;
    x[j] = sinf(a);
    x[j + 64] = cosf(a);
  }
  __syncthreads();
  for (int o = j; o < 256; o += 128) {
    float acc = tm_b1[o];
    for (int k = 0; k < 128; ++k) acc = fmaf(x[k], tm_W1[k * 256 + o], acc);
    hid[o] = silu_f(acc);
  }
  __syncthreads();
  {
    float acc = tm_b2[j];
    for (int k = 0; k < 256; ++k) acc = fmaf(hid[k], tm_W2[k * 128 + j], acc);
    te[j] = acc;
    temb[g * 128 + j] = acc;
  }
  __syncthreads();
  for (int l = 0; l < LL; ++l) {
    const float* W = eW1 + (l * 385 + 257) * 128;
    float acc = eb1[l * 128 + j];
    for (int k = 0; k < 128; ++k) acc = fmaf(te[k], W[k * 128 + j], acc);
    tE[(l * GN + g) * 128 + j] = acc;
    const float* Wn = nW1 + (l * 384 + 256) * 128;
    float acc2 = nb1[l * 128 + j];
    for (int k = 0; k < 128; ++k) acc2 = fmaf(te[k], Wn[k * 128 + j], acc2);
    tN[(l * GN + g) * 128 + j] = acc2;
  }
}

// ---------------------------------------------------------------------------
// Weight prep: fp32 [K][128] -> bf16 transposed [n][k] (exact RNE).
// ---------------------------------------------------------------------------
__global__ __launch_bounds__(256) void prep_transpose(
    const float* __restrict__ eW1, const float* __restrict__ eW2,
    const float* __restrict__ cW1, const float* __restrict__ nW1,
    const float* __restrict__ nW2, const float* __restrict__ ne_W,
    unsigned short* __restrict__ eABt, unsigned short* __restrict__ eW2t,
    unsigned short* __restrict__ cW1t, unsigned short* __restrict__ nW1t,
    unsigned short* __restrict__ nW2t, unsigned short* __restrict__ ne_Wt)
{
  __shared__ float tile[32][33];
  int j = blockIdx.y;
  const float* src;
  unsigned short* dst;
  int dstride = 128, Kj = 128;
  if (j < 28) {
    int l = j / 7, m = j % 7;
    switch (m) {
      case 0: src = eW1 + (l * 385 + 0) * 128;   dst = eABt + l * 256 * 128;             break;
      case 1: src = eW1 + (l * 385 + 128) * 128; dst = eABt + l * 256 * 128 + 128 * 128; break;
      case 2: src = eW2 + l * 16384;             dst = eW2t + l * 16384;                 break;
      case 3: src = cW1 + l * 16384;             dst = cW1t + l * 16384;                 break;
      case 4: src = nW1 + (l * 384 + 0) * 128;   dst = nW1t + l * 128 * 256; dstride = 256; break;
      case 5: src = nW1 + (l * 384 + 128) * 128; dst = nW1t + l * 128 * 256 + 128; dstride = 256; break;
      default: src = nW2 + l * 16384;            dst = nW2t + l * 16384;                 break;
    }
  } else {
    src = ne_W; dst = ne_Wt; dstride = 160; Kj = 160;
  }
  int gx = blockIdx.x;
  int tk = (gx % 5) * 32;
  int tn = (gx / 5) * 32;
  if (tk >= Kj) return;
  int ti = threadIdx.x >> 5, tj = threadIdx.x & 31;
#pragma unroll
  for (int p = 0; p < 4; ++p) {
    int i = ti + p * 8;
    tile[i][tj] = src[(tk + i) * 128 + tn + tj];
  }
  __syncthreads();
#pragma unroll
  for (int p = 0; p < 4; ++p) {
    int i = ti + p * 8;
    dst[(tn + i) * dstride + tk + tj] = f2bu(tile[tj][i]);
  }
}

// ---------------------------------------------------------------------------
// Edge pipeline: 1 wave per block, 2 chunks of 48 edges = 8 nodes per wave.
// mt-outer loops reuse each weight fragment across both chunks (halves weight
// VMEM per unit work, doubles MFMA run length). Round-4-proven structure.
// ---------------------------------------------------------------------------
__global__ __launch_bounds__(64) void edge_mfma(
    const unsigned short* __restrict__ hAB,   // [NN][256] bf16
    const float* __restrict__ coords, const int* __restrict__ edge_src,
    const float* __restrict__ eW1,            // fp32 (dist_sq row)
    const unsigned short* __restrict__ eW2t, const float* __restrict__ eb2,
    const unsigned short* __restrict__ cW1t, const float* __restrict__ cb1,
    const float* __restrict__ cW2, const float* __restrict__ tE,
    unsigned short* __restrict__ m_i, float* __restrict__ shift_out,
    int l, int addflag)
{
  __shared__ unsigned short mbuf[2][48 * 136];
  __shared__ float sdir[2][48 * 4];
  __shared__ float sgate[2][48];

  int l6 = threadIdx.x;
  int e16 = l6 & 15, q = l6 >> 4;
  int nbase0 = blockIdx.x * 8;

  const unsigned short* eW2t_l = eW2t + l * 16384;
  const unsigned short* cW1t_l = cW1t + l * 16384;
  const float* eb2_l = eb2 + l * 128;
  const float* cb1_l = cb1 + l * 128;
  const float* cW2_l = cW2 + l * 128;
  const float* tE_l = tE + l * GN * 128;
  const float* wd = eW1 + (l * 385 + 256) * 128;

  // geometry
  int ssrc[2][3], sdst[2][3];
  float sds[2][3];
#pragma unroll
  for (int c = 0; c < 2; ++c) {
    int nbase = nbase0 + c * 4;
    int ebase = nbase * 12;
#pragma unroll
    for (int grp = 0; grp < 3; ++grp) {
      int eloc = grp * 16 + e16;
      int e = ebase + eloc;
      int src = edge_src[e];
      src = min(max(src, 0), NN - 1);
      int dst = nbase + eloc / 12;
      float dx = coords[src * 3 + 0] - coords[dst * 3 + 0];
      float dy = coords[src * 3 + 1] - coords[dst * 3 + 1];
      float dz = coords[src * 3 + 2] - coords[dst * 3 + 2];
      float ds = dx * dx + dy * dy + dz * dz;
      float rinv = 1.0f / sqrtf(ds + 1e-8f);
      if (q == 0) {
        sdir[c][eloc * 4 + 0] = dx * rinv;
        sdir[c][eloc * 4 + 1] = dy * rinv;
        sdir[c][eloc * 4 + 2] = dz * rinv;
      }
      ssrc[c][grp] = src; sdst[c][grp] = dst; sds[c][grp] = ds;
    }
  }

  // Phase A: m1 B-fragments in registers
  short8 bfr[2][3][4];
#pragma unroll
  for (int c = 0; c < 2; ++c)
#pragma unroll
  for (int grp = 0; grp < 3; ++grp) {
    int g = sdst[c][grp] / NPER;
    float ds = sds[c][grp];
#pragma unroll
    for (int kc = 0; kc < 4; ++kc) {
      int k0 = kc * 32 + q * 8;
      uint4 ua = *(const uint4*)(hAB + ssrc[c][grp] * 256 + k0);
      uint4 ub = *(const uint4*)(hAB + sdst[c][grp] * 256 + 128 + k0);
      float4 w0 = *(const float4*)(wd + k0);
      float4 w1 = *(const float4*)(wd + k0 + 4);
      float4 t0 = *(const float4*)(tE_l + g * 128 + k0);
      float4 t1 = *(const float4*)(tE_l + g * 128 + k0 + 4);
      float v[8];
      v[0] = silu_f(blo(ua.x) + blo(ub.x) + ds * w0.x + t0.x);
      v[1] = silu_f(bhi(ua.x) + bhi(ub.x) + ds * w0.y + t0.y);
      v[2] = silu_f(blo(ua.y) + blo(ub.y) + ds * w0.z + t0.z);
      v[3] = silu_f(bhi(ua.y) + bhi(ub.y) + ds * w0.w + t0.w);
      v[4] = silu_f(blo(ua.z) + blo(ub.z) + ds * w1.x + t1.x);
      v[5] = silu_f(bhi(ua.z) + bhi(ub.z) + ds * w1.y + t1.y);
      v[6] = silu_f(blo(ua.w) + blo(ub.w) + ds * w1.z + t1.z);
      v[7] = silu_f(bhi(ua.w) + bhi(ub.w) + ds * w1.w + t1.w);
      bfr[c][grp][kc] = pack8(v);
    }
  }

  // GEMM1 (transposed): m2^T = eW2^T @ m1^T; weight frags reused across chunks
#pragma unroll
  for (int mt = 0; mt < 8; ++mt) {
    short8 af[4];
#pragma unroll
    for (int kc = 0; kc < 4; ++kc)
      af[kc] = *(const short8*)(eW2t_l + (mt * 16 + e16) * 128 + kc * 32 + q * 8);
    f32x4 acc[2][3];
#pragma unroll
    for (int c = 0; c < 2; ++c)
#pragma unroll
      for (int grp = 0; grp < 3; ++grp) acc[c][grp] = (f32x4){0, 0, 0, 0};
#pragma unroll
    for (int kc = 0; kc < 4; ++kc)
#pragma unroll
      for (int c = 0; c < 2; ++c)
#pragma unroll
        for (int grp = 0; grp < 3; ++grp)
          acc[c][grp] = __builtin_amdgcn_mfma_f32_16x16x32_bf16(af[kc], bfr[c][grp][kc], acc[c][grp], 0, 0, 0);
    float4 b4 = *(const float4*)(eb2_l + mt * 16 + q * 4);
#pragma unroll
    for (int c = 0; c < 2; ++c)
#pragma unroll
      for (int grp = 0; grp < 3; ++grp) {
        float v0 = silu_f(acc[c][grp][0] + b4.x);
        float v1 = silu_f(acc[c][grp][1] + b4.y);
        float v2 = silu_f(acc[c][grp][2] + b4.z);
        float v3 = silu_f(acc[c][grp][3] + b4.w);
        uint2 p;
        p.x = pack2bf(v0, v1);
        p.y = pack2bf(v2, v3);
        *(uint2*)&mbuf[c][(grp * 16 + e16) * 136 + mt * 16 + q * 4] = p;
      }
  }
  __syncthreads();  // single wave: ordering only

  // GEMM2: g = m2 @ cW1; gate = g . cW2 (in-register reduce)
  short8 af2[2][3][4];
#pragma unroll
  for (int c = 0; c < 2; ++c)
#pragma unroll
    for (int grp = 0; grp < 3; ++grp)
#pragma unroll
      for (int kc = 0; kc < 4; ++kc)
        af2[c][grp][kc] = *(const short8*)&mbuf[c][(grp * 16 + e16) * 136 + kc * 32 + q * 8];

  float gp[2][3][4] = {{{0,0,0,0},{0,0,0,0},{0,0,0,0}},
                       {{0,0,0,0},{0,0,0,0},{0,0,0,0}}};
#pragma unroll
  for (int ct = 0; ct < 8; ++ct) {
    short8 bf[4];
#pragma unroll
    for (int kc = 0; kc < 4; ++kc)
      bf[kc] = *(const short8*)(cW1t_l + (ct * 16 + e16) * 128 + kc * 32 + q * 8);
    f32x4 acc[2][3];
#pragma unroll
    for (int c = 0; c < 2; ++c)
#pragma unroll
      for (int grp = 0; grp < 3; ++grp) acc[c][grp] = (f32x4){0, 0, 0, 0};
#pragma unroll
    for (int kc = 0; kc < 4; ++kc)
#pragma unroll
      for (int c = 0; c < 2; ++c)
#pragma unroll
        for (int grp = 0; grp < 3; ++grp)
          acc[c][grp] = __builtin_amdgcn_mfma_f32_16x16x32_bf16(af2[c][grp][kc], bf[kc], acc[c][grp], 0, 0, 0);
    float cb = cb1_l[ct * 16 + e16];
    float c2 = cW2_l[ct * 16 + e16];
#pragma unroll
    for (int c = 0; c < 2; ++c)
#pragma unroll
      for (int grp = 0; grp < 3; ++grp)
#pragma unroll
        for (int r = 0; r < 4; ++r)
          gp[c][grp][r] += silu_f(acc[c][grp][r] + cb) * c2;
  }
#pragma unroll
  for (int c = 0; c < 2; ++c)
#pragma unroll
    for (int grp = 0; grp < 3; ++grp)
#pragma unroll
      for (int r = 0; r < 4; ++r) {
        float v = gp[c][grp][r];
        v += __shfl_xor(v, 1);
        v += __shfl_xor(v, 2);
        v += __shfl_xor(v, 4);
        v += __shfl_xor(v, 8);
        if (e16 == 0) sgate[c][grp * 16 + q * 4 + r] = v;
      }
  __syncthreads();  // ordering

  // m_i: node = q (within chunk), col-chunk = e16*8 (bf16 out)
#pragma unroll
  for (int c = 0; c < 2; ++c) {
    int nl = q, c8 = e16 * 8;
    float s[8] = {0,0,0,0,0,0,0,0};
#pragma unroll
    for (int r = 0; r < 12; ++r) {
      uint4 u = *(const uint4*)&mbuf[c][(nl * 12 + r) * 136 + c8];
      s[0] += blo(u.x); s[1] += bhi(u.x);
      s[2] += blo(u.y); s[3] += bhi(u.y);
      s[4] += blo(u.z); s[5] += bhi(u.z);
      s[6] += blo(u.w); s[7] += bhi(u.w);
    }
    uint4 o;
    o.x = pack2bf(s[0], s[1]); o.y = pack2bf(s[2], s[3]);
    o.z = pack2bf(s[4], s[5]); o.w = pack2bf(s[6], s[7]);
    *(uint4*)(m_i + (nbase0 + c * 4 + nl) * 128 + c8) = o;
  }
  // shift: 8 nodes x 3 comps = 24 lanes
  if (l6 < 24) {
    int nl8 = l6 / 3, comp = l6 - nl8 * 3;
    int c = nl8 >> 2, nl = nl8 & 3;
    float s = 0.f;
#pragma unroll
    for (int r = 0; r < 12; ++r) {
      int e = nl * 12 + r;
      s = fmaf(sdir[c][e * 4 + comp], sgate[c][e], s);
    }
    int n = nbase0 + c * 4 + nl;
    if (addflag) shift_out[n * 3 + comp] += s;
    else         shift_out[n * 3 + comp] = s;
  }
}

// ---------------------------------------------------------------------------
// Fused node MLP (round-4 proven shape, 1 wave, 16 rows):
// h += silu([h|m_i]@nW1 + tN) @ nW2 + nb2; then (optional) hAB = h @ eABt_next
// ---------------------------------------------------------------------------
__global__ __launch_bounds__(64) void node_mfma(
    float* __restrict__ h, const unsigned short* __restrict__ m_i,
    const unsigned short* __restrict__ nW1t_l, const unsigned short* __restrict__ nW2t_l,
    const float* __restrict__ nb2_l, const float* __restrict__ tN_l,
    const unsigned short* __restrict__ eABt_next, unsigned short* __restrict__ hAB,
    int has_c)
{
  __shared__ unsigned short z1buf[16 * 136];
  __shared__ unsigned short hbuf[16 * 136];
  int l6 = threadIdx.x, e16 = l6 & 15, q = l6 >> 4;
  int row = blockIdx.x * 16 + e16;
  int g = row / NPER;

  short8 bfh[8];
#pragma unroll
  for (int kc = 0; kc < 8; ++kc) {
    int k0 = kc * 32 + q * 8;
    if (k0 < 128) {
      float4 f0 = *(const float4*)(h + row * 128 + k0);
      float4 f1 = *(const float4*)(h + row * 128 + k0 + 4);
      float v[8] = {f0.x, f0.y, f0.z, f0.w, f1.x, f1.y, f1.z, f1.w};
      bfh[kc] = pack8(v);
    } else {
      bfh[kc] = *(const short8*)(m_i + row * 128 + (k0 - 128));
    }
  }
#pragma unroll
  for (int mt = 0; mt < 8; ++mt) {
    short8 af[8];
#pragma unroll
    for (int kc = 0; kc < 8; ++kc)
      af[kc] = *(const short8*)(nW1t_l + (mt * 16 + e16) * 256 + kc * 32 + q * 8);
    f32x4 acc = (f32x4){0,0,0,0};
#pragma unroll
    for (int kc = 0; kc < 8; ++kc)
      acc = __builtin_amdgcn_mfma_f32_16x16x32_bf16(af[kc], bfh[kc], acc, 0, 0, 0);
    float4 tv = *(const float4*)(tN_l + g * 128 + mt * 16 + q * 4);
    float v0 = silu_f(acc[0] + tv.x);
    float v1 = silu_f(acc[1] + tv.y);
    float v2 = silu_f(acc[2] + tv.z);
    float v3 = silu_f(acc[3] + tv.w);
    uint2 p; p.x = pack2bf(v0, v1); p.y = pack2bf(v2, v3);
    *(uint2*)&z1buf[e16 * 136 + mt * 16 + q * 4] = p;
  }
  __syncthreads();

  short8 zf[4];
#pragma unroll
  for (int kc = 0; kc < 4; ++kc)
    zf[kc] = *(const short8*)&z1buf[e16 * 136 + kc * 32 + q * 8];
#pragma unroll
  for (int mt = 0; mt < 8; ++mt) {
    short8 af[4];
#pragma unroll
    for (int kc = 0; kc < 4; ++kc)
      af[kc] = *(const short8*)(nW2t_l + (mt * 16 + e16) * 128 + kc * 32 + q * 8);
    f32x4 acc = (f32x4){0,0,0,0};
#pragma unroll
    for (int kc = 0; kc < 4; ++kc)
      acc = __builtin_amdgcn_mfma_f32_16x16x32_bf16(af[kc], zf[kc], acc, 0, 0, 0);
    float4 hv = *(const float4*)(h + row * 128 + mt * 16 + q * 4);
    float4 b4 = *(const float4*)(nb2_l + mt * 16 + q * 4);
    float4 o;
    o.x = hv.x + acc[0] + b4.x;
    o.y = hv.y + acc[1] + b4.y;
    o.z = hv.z + acc[2] + b4.z;
    o.w = hv.w + acc[3] + b4.w;
    *(float4*)(h + row * 128 + mt * 16 + q * 4) = o;
    uint2 p; p.x = pack2bf(o.x, o.y); p.y = pack2bf(o.z, o.w);
    *(uint2*)&hbuf[e16 * 136 + mt * 16 + q * 4] = p;
  }
  if (has_c) {
    __syncthreads();
    short8 hf[4];
#pragma unroll
    for (int kc = 0; kc < 4; ++kc)
      hf[kc] = *(const short8*)&hbuf[e16 * 136 + kc * 32 + q * 8];
#pragma unroll
    for (int mt = 0; mt < 16; ++mt) {
      short8 af[4];
#pragma unroll
      for (int kc = 0; kc < 4; ++kc)
        af[kc] = *(const short8*)(eABt_next + (mt * 16 + e16) * 128 + kc * 32 + q * 8);
      f32x4 acc = (f32x4){0,0,0,0};
#pragma unroll
      for (int kc = 0; kc < 4; ++kc)
        acc = __builtin_amdgcn_mfma_f32_16x16x32_bf16(af[kc], hf[kc], acc, 0, 0, 0);
      uint2 p; p.x = pack2bf(acc[0], acc[1]); p.y = pack2bf(acc[2], acc[3]);
      *(uint2*)(hAB + row * 256 + mt * 16 + q * 4) = p;
    }
  }
}

// ---------------------------------------------------------------------------
// Fused encoder (round-4 shape): h = [z|sp]@ne_W + ne_b; hAB = h@eABt[0]
// ---------------------------------------------------------------------------
__global__ __launch_bounds__(64) void encoder_mfma(
    const float* __restrict__ z, const int* __restrict__ species,
    const float* __restrict__ species_emb,
    const unsigned short* __restrict__ ne_Wt, const float* __restrict__ ne_b,
    const unsigned short* __restrict__ eABt0,
    float* __restrict__ h, unsigned short* __restrict__ hAB)
{
  __shared__ unsigned short hbuf[16 * 136];
  int l6 = threadIdx.x, e16 = l6 & 15, q = l6 >> 4;
  int row = blockIdx.x * 16 + e16;
  int sp = species[row];
  sp = min(max(sp, 0), 118);

  short8 bfh[5];
#pragma unroll
  for (int kc = 0; kc < 5; ++kc) {
    int k0 = kc * 32 + q * 8;
    const float* src = (k0 < 128) ? (z + row * 128 + k0)
                                  : (species_emb + sp * 32 + (k0 - 128));
    float4 f0 = *(const float4*)src;
    float4 f1 = *(const float4*)(src + 4);
    float v[8] = {f0.x, f0.y, f0.z, f0.w, f1.x, f1.y, f1.z, f1.w};
    bfh[kc] = pack8(v);
  }
#pragma unroll
  for (int mt = 0; mt < 8; ++mt) {
    short8 af[5];
#pragma unroll
    for (int kc = 0; kc < 5; ++kc)
      af[kc] = *(const short8*)(ne_Wt + (mt * 16 + e16) * 160 + kc * 32 + q * 8);
    f32x4 acc = (f32x4){0,0,0,0};
#pragma unroll
    for (int kc = 0; kc < 5; ++kc)
      acc = __builtin_amdgcn_mfma_f32_16x16x32_bf16(af[kc], bfh[kc], acc, 0, 0, 0);
    float4 b4 = *(const float4*)(ne_b + mt * 16 + q * 4);
    float4 o;
    o.x = acc[0] + b4.x; o.y = acc[1] + b4.y;
    o.z = acc[2] + b4.z; o.w = acc[3] + b4.w;
    *(float4*)(h + row * 128 + mt * 16 + q * 4) = o;
    uint2 p; p.x = pack2bf(o.x, o.y); p.y = pack2bf(o.z, o.w);
    *(uint2*)&hbuf[e16 * 136 + mt * 16 + q * 4] = p;
  }
  __syncthreads();
  short8 hf[4];
#pragma unroll
  for (int kc = 0; kc < 4; ++kc)
    hf[kc] = *(const short8*)&hbuf[e16 * 136 + kc * 32 + q * 8];
#pragma unroll
  for (int mt = 0; mt < 16; ++mt) {
    short8 af[4];
#pragma unroll
    for (int kc = 0; kc < 4; ++kc)
      af[kc] = *(const short8*)(eABt0 + (mt * 16 + e16) * 128 + kc * 32 + q * 8);
    f32x4 acc = (f32x4){0,0,0,0};
#pragma unroll
    for (int kc = 0; kc < 4; ++kc)
      acc = __builtin_amdgcn_mfma_f32_16x16x32_bf16(af[kc], hf[kc], acc, 0, 0, 0);
    uint2 p; p.x = pack2bf(acc[0], acc[1]); p.y = pack2bf(acc[2], acc[3]);
    *(uint2*)(hAB + row * 256 + mt * 16 + q * 4) = p;
  }
}

extern "C" void kernel_launch(void* const* d_in, const int* in_sizes, int n_in,
                              void* d_out, int out_size, void* d_ws, size_t ws_size,
                              hipStream_t stream)
{
  const float* z_nodes     = (const float*)d_in[0];
  const float* t           = (const float*)d_in[1];
  const float* coords      = (const float*)d_in[2];
  const int*   species     = (const int*)d_in[3];
  const int*   edge_src    = (const int*)d_in[5];
  const float* species_emb = (const float*)d_in[7];
  const float* tm_W1 = (const float*)d_in[8];
  const float* tm_b1 = (const float*)d_in[9];
  const float* tm_W2 = (const float*)d_in[10];
  const float* tm_b2 = (const float*)d_in[11];
  const float* ne_W  = (const float*)d_in[12];
  const float* ne_b  = (const float*)d_in[13];
  const float* eW1   = (const float*)d_in[14];
  const float* eb1   = (const float*)d_in[15];
  const float* eW2   = (const float*)d_in[16];
  const float* eb2   = (const float*)d_in[17];
  const float* cW1   = (const float*)d_in[18];
  const float* cb1   = (const float*)d_in[19];
  const float* cW2   = (const float*)d_in[20];
  const float* nW1   = (const float*)d_in[21];
  const float* nb1   = (const float*)d_in[22];
  const float* nW2   = (const float*)d_in[23];
  const float* nb2   = (const float*)d_in[24];

  char* wsb = (char*)d_ws;
  float* temb = (float*)(wsb + 0);                          // 204800 B
  float* tEb  = (float*)(wsb + 204800);                     // 819200 B
  float* tNb  = (float*)(wsb + 1024000);                    // 819200 B
  unsigned short* hAB  = (unsigned short*)(wsb + 1843200);  // 10,240,000 B
  unsigned short* m_i  = (unsigned short*)(wsb + 12083200); // 5,120,000 B (bf16)
  unsigned short* eABt = (unsigned short*)(wsb + 17203200); // 262144
  unsigned short* eW2t = (unsigned short*)(wsb + 17465344); // 131072
  unsigned short* cW1t = (unsigned short*)(wsb + 17596416); // 131072
  unsigned short* nW1t = (unsigned short*)(wsb + 17727488); // 262144
  unsigned short* nW2t = (unsigned short*)(wsb + 17989632); // 131072
  unsigned short* ne_Wt= (unsigned short*)(wsb + 18120704); // 40960
  // total: 18,161,664 B

  float* outp  = (float*)d_out;
  float* shift = outp;            // [20000,3]
  float* h     = outp + 60000;    // [20000,128]

  time_kernel<<<GN, 128, 0, stream>>>(t, tm_W1, tm_b1, tm_W2, tm_b2,
                                      eW1, eb1, nW1, nb1, temb, tEb, tNb);
  prep_transpose<<<dim3(20, 29), 256, 0, stream>>>(eW1, eW2, cW1, nW1, nW2, ne_W,
                                                   eABt, eW2t, cW1t, nW1t, nW2t, ne_Wt);
  encoder_mfma<<<NN / 16, 64, 0, stream>>>(z_nodes, species, species_emb,
                                           ne_Wt, ne_b, eABt, h, hAB);
  for (int l = 0; l < LL; ++l) {
    edge_mfma<<<NN / 8, 64, 0, stream>>>(hAB, coords, edge_src, eW1,
                                         eW2t, eb2, cW1t, cb1, cW2, tEb,
                                         m_i, shift, l, (l > 0) ? 1 : 0);
    int has_c = (l < LL - 1) ? 1 : 0;
    node_mfma<<<NN / 16, 64, 0, stream>>>(h, m_i,
                                          nW1t + l * 128 * 256, nW2t + l * 16384,
                                          nb2 + l * 128, tNb + l * GN * 128,
                                          has_c ? (eABt + (l + 1) * 256 * 128) : eABt,
                                          hAB, has_c);
  }
}

// Round 7
// 573.589 us; speedup vs baseline: 1.0629x; 1.0629x over previous
//
#include <hip/hip_runtime.h>
#include <math.h>

#define GN 400
#define NPER 50
#define NN 20000
#define LL 4

typedef __attribute__((ext_vector_type(8))) short short8;
typedef __attribute__((ext_vector_type(4))) float f32x4;

__device__ __forceinline__ float fast_rcp(float x) {
#if __has_builtin(__builtin_amdgcn_rcpf)
  return __builtin_amdgcn_rcpf(x);
#else
  return 1.0f / x;
#endif
}
__device__ __forceinline__ float silu_f(float x) {
  return x * fast_rcp(1.0f + __expf(-x));
}
// Exact RNE (weights only)
__device__ __forceinline__ unsigned short f2bu(float f) {
  unsigned int u = __float_as_uint(f);
  unsigned int r = (u + 0x7fffu + ((u >> 16) & 1u)) >> 16;
  return (unsigned short)r;
}
// Fast round-half-up pack: 2 adds + 1 v_perm
__device__ __forceinline__ unsigned int pack2bf(float lo, float hi) {
  unsigned int a = __float_as_uint(lo) + 0x8000u;
  unsigned int b = __float_as_uint(hi) + 0x8000u;
#if __has_builtin(__builtin_amdgcn_perm)
  return __builtin_amdgcn_perm(b, a, 0x07060302);
#else
  return (b & 0xffff0000u) | (a >> 16);
#endif
}
__device__ __forceinline__ float bhi(unsigned int u) { return __uint_as_float(u & 0xffff0000u); }
__device__ __forceinline__ float blo(unsigned int u) { return __uint_as_float(u << 16); }

__device__ __forceinline__ short8 pack8(const float* v) {
  union { unsigned int u[4]; short8 s; } t;
  t.u[0] = pack2bf(v[0], v[1]);
  t.u[1] = pack2bf(v[2], v[3]);
  t.u[2] = pack2bf(v[4], v[5]);
  t.u[3] = pack2bf(v[6], v[7]);
  return t.s;
}

// ---------------------------------------------------------------------------
// Time embedding MLP + per-layer per-graph t-projections (400 graphs)
// ---------------------------------------------------------------------------
__global__ __launch_bounds__(128) void time_kernel(
    const float* __restrict__ t,
    const float* __restrict__ tm_W1, const float* __restrict__ tm_b1,
    const float* __restrict__ tm_W2, const float* __restrict__ tm_b2,
    const float* __restrict__ eW1, const float* __restrict__ eb1,
    const float* __restrict__ nW1, const float* __restrict__ nb1,
    float* __restrict__ temb, float* __restrict__ tE, float* __restrict__ tN)
{
  int g = blockIdx.x;
  int j = threadIdx.x;
  __shared__ float x[128];
  __shared__ float hid[256];
  __shared__ float te[128];
  float tv = t[g];
  if (j < 64) {
    float f = __expf((float)j * (-9.210340371976184f / 63.0f));
    float a = tv * f;
    x[j] = sinf(a);
    x[j + 64] = cosf(a);
  }
  __syncthreads();
  for (int o = j; o < 256; o += 128) {
    float acc = tm_b1[o];
    for (int k = 0; k < 128; ++k) acc = fmaf(x[k], tm_W1[k * 256 + o], acc);
    hid[o] = silu_f(acc);
  }
  __syncthreads();
  {
    float acc = tm_b2[j];
    for (int k = 0; k < 256; ++k) acc = fmaf(hid[k], tm_W2[k * 128 + j], acc);
    te[j] = acc;
    temb[g * 128 + j] = acc;
  }
  __syncthreads();
  for (int l = 0; l < LL; ++l) {
    const float* W = eW1 + (l * 385 + 257) * 128;
    float acc = eb1[l * 128 + j];
    for (int k = 0; k < 128; ++k) acc = fmaf(te[k], W[k * 128 + j], acc);
    tE[(l * GN + g) * 128 + j] = acc;
    const float* Wn = nW1 + (l * 384 + 256) * 128;
    float acc2 = nb1[l * 128 + j];
    for (int k = 0; k < 128; ++k) acc2 = fmaf(te[k], Wn[k * 128 + j], acc2);
    tN[(l * GN + g) * 128 + j] = acc2;
  }
}

// ---------------------------------------------------------------------------
// Weight prep: fp32 [K][128] -> bf16 transposed [n][k] (exact RNE).
// ---------------------------------------------------------------------------
__global__ __launch_bounds__(256) void prep_transpose(
    const float* __restrict__ eW1, const float* __restrict__ eW2,
    const float* __restrict__ cW1, const float* __restrict__ nW1,
    const float* __restrict__ nW2, const float* __restrict__ ne_W,
    unsigned short* __restrict__ eABt, unsigned short* __restrict__ eW2t,
    unsigned short* __restrict__ cW1t, unsigned short* __restrict__ nW1t,
    unsigned short* __restrict__ nW2t, unsigned short* __restrict__ ne_Wt)
{
  __shared__ float tile[32][33];
  int j = blockIdx.y;
  const float* src;
  unsigned short* dst;
  int dstride = 128, Kj = 128;
  if (j < 28) {
    int l = j / 7, m = j % 7;
    switch (m) {
      case 0: src = eW1 + (l * 385 + 0) * 128;   dst = eABt + l * 256 * 128;             break;
      case 1: src = eW1 + (l * 385 + 128) * 128; dst = eABt + l * 256 * 128 + 128 * 128; break;
      case 2: src = eW2 + l * 16384;             dst = eW2t + l * 16384;                 break;
      case 3: src = cW1 + l * 16384;             dst = cW1t + l * 16384;                 break;
      case 4: src = nW1 + (l * 384 + 0) * 128;   dst = nW1t + l * 128 * 256; dstride = 256; break;
      case 5: src = nW1 + (l * 384 + 128) * 128; dst = nW1t + l * 128 * 256 + 128; dstride = 256; break;
      default: src = nW2 + l * 16384;            dst = nW2t + l * 16384;                 break;
    }
  } else {
    src = ne_W; dst = ne_Wt; dstride = 160; Kj = 160;
  }
  int gx = blockIdx.x;
  int tk = (gx % 5) * 32;
  int tn = (gx / 5) * 32;
  if (tk >= Kj) return;
  int ti = threadIdx.x >> 5, tj = threadIdx.x & 31;
#pragma unroll
  for (int p = 0; p < 4; ++p) {
    int i = ti + p * 8;
    tile[i][tj] = src[(tk + i) * 128 + tn + tj];
  }
  __syncthreads();
#pragma unroll
  for (int p = 0; p < 4; ++p) {
    int i = ti + p * 8;
    dst[(tn + i) * dstride + tk + tj] = f2bu(tile[tj][i]);
  }
}

// ---------------------------------------------------------------------------
// Edge pipeline: EXACT round-4 structure (proven 74 us). 1 wave per block,
// 48 edges = 4 nodes. Single-wave syncs compile to waitcnt only.
// ---------------------------------------------------------------------------
__global__ __launch_bounds__(64) void edge_mfma(
    const unsigned short* __restrict__ hAB,   // [NN][256] bf16
    const float* __restrict__ coords, const int* __restrict__ edge_src,
    const float* __restrict__ eW1,            // fp32 (dist_sq row)
    const unsigned short* __restrict__ eW2t, const float* __restrict__ eb2,
    const unsigned short* __restrict__ cW1t, const float* __restrict__ cb1,
    const float* __restrict__ cW2, const float* __restrict__ tE,
    unsigned short* __restrict__ m_i, float* __restrict__ shift_out,
    int l, int addflag)
{
  __shared__ unsigned short mbuf[48 * 136];
  __shared__ float sdir[48 * 4];
  __shared__ float sgate[48];

  int l6 = threadIdx.x;
  int e16 = l6 & 15, q = l6 >> 4;
  int nbase = blockIdx.x * 4;
  int ebase = blockIdx.x * 48;

  const unsigned short* eW2t_l = eW2t + l * 16384;
  const unsigned short* cW1t_l = cW1t + l * 16384;
  const float* eb2_l = eb2 + l * 128;
  const float* cb1_l = cb1 + l * 128;
  const float* cW2_l = cW2 + l * 128;
  const float* tE_l = tE + l * GN * 128;
  const float* wd = eW1 + (l * 385 + 256) * 128;

  int ssrc[3], sdst[3];
  float sds[3];
#pragma unroll
  for (int grp = 0; grp < 3; ++grp) {
    int eloc = grp * 16 + e16;
    int e = ebase + eloc;
    int src = edge_src[e];
    src = min(max(src, 0), NN - 1);
    int dst = nbase + eloc / 12;
    float dx = coords[src * 3 + 0] - coords[dst * 3 + 0];
    float dy = coords[src * 3 + 1] - coords[dst * 3 + 1];
    float dz = coords[src * 3 + 2] - coords[dst * 3 + 2];
    float ds = dx * dx + dy * dy + dz * dz;
    float rinv = 1.0f / sqrtf(ds + 1e-8f);
    if (q == 0) {
      sdir[eloc * 4 + 0] = dx * rinv;
      sdir[eloc * 4 + 1] = dy * rinv;
      sdir[eloc * 4 + 2] = dz * rinv;
    }
    ssrc[grp] = src; sdst[grp] = dst; sds[grp] = ds;
  }

  // Phase A: m1 B-fragments in registers
  short8 bfr[3][4];
#pragma unroll
  for (int grp = 0; grp < 3; ++grp) {
    int g = sdst[grp] / NPER;
    float ds = sds[grp];
#pragma unroll
    for (int kc = 0; kc < 4; ++kc) {
      int k0 = kc * 32 + q * 8;
      uint4 ua = *(const uint4*)(hAB + ssrc[grp] * 256 + k0);
      uint4 ub = *(const uint4*)(hAB + sdst[grp] * 256 + 128 + k0);
      float4 w0 = *(const float4*)(wd + k0);
      float4 w1 = *(const float4*)(wd + k0 + 4);
      float4 t0 = *(const float4*)(tE_l + g * 128 + k0);
      float4 t1 = *(const float4*)(tE_l + g * 128 + k0 + 4);
      float v[8];
      v[0] = silu_f(blo(ua.x) + blo(ub.x) + ds * w0.x + t0.x);
      v[1] = silu_f(bhi(ua.x) + bhi(ub.x) + ds * w0.y + t0.y);
      v[2] = silu_f(blo(ua.y) + blo(ub.y) + ds * w0.z + t0.z);
      v[3] = silu_f(bhi(ua.y) + bhi(ub.y) + ds * w0.w + t0.w);
      v[4] = silu_f(blo(ua.z) + blo(ub.z) + ds * w1.x + t1.x);
      v[5] = silu_f(bhi(ua.z) + bhi(ub.z) + ds * w1.y + t1.y);
      v[6] = silu_f(blo(ua.w) + blo(ub.w) + ds * w1.z + t1.z);
      v[7] = silu_f(bhi(ua.w) + bhi(ub.w) + ds * w1.w + t1.w);
      bfr[grp][kc] = pack8(v);
    }
  }

  // GEMM1 (transposed): m2^T = eW2^T @ m1^T -> packed b64 writes
#pragma unroll
  for (int mt = 0; mt < 8; ++mt) {
    short8 af[4];
#pragma unroll
    for (int kc = 0; kc < 4; ++kc)
      af[kc] = *(const short8*)(eW2t_l + (mt * 16 + e16) * 128 + kc * 32 + q * 8);
    f32x4 acc[3] = {(f32x4){0,0,0,0}, (f32x4){0,0,0,0}, (f32x4){0,0,0,0}};
#pragma unroll
    for (int kc = 0; kc < 4; ++kc) {
#pragma unroll
      for (int grp = 0; grp < 3; ++grp)
        acc[grp] = __builtin_amdgcn_mfma_f32_16x16x32_bf16(af[kc], bfr[grp][kc], acc[grp], 0, 0, 0);
    }
    float4 b4 = *(const float4*)(eb2_l + mt * 16 + q * 4);
#pragma unroll
    for (int grp = 0; grp < 3; ++grp) {
      float v0 = silu_f(acc[grp][0] + b4.x);
      float v1 = silu_f(acc[grp][1] + b4.y);
      float v2 = silu_f(acc[grp][2] + b4.z);
      float v3 = silu_f(acc[grp][3] + b4.w);
      uint2 p;
      p.x = pack2bf(v0, v1);
      p.y = pack2bf(v2, v3);
      *(uint2*)&mbuf[(grp * 16 + e16) * 136 + mt * 16 + q * 4] = p;
    }
  }
  __syncthreads();  // single wave: waitcnt only

  // GEMM2: g = m2 @ cW1; gate = g . cW2
  short8 af2[3][4];
#pragma unroll
  for (int grp = 0; grp < 3; ++grp)
#pragma unroll
    for (int kc = 0; kc < 4; ++kc)
      af2[grp][kc] = *(const short8*)&mbuf[(grp * 16 + e16) * 136 + kc * 32 + q * 8];

  float gp[3][4] = {{0,0,0,0},{0,0,0,0},{0,0,0,0}};
#pragma unroll
  for (int ct = 0; ct < 8; ++ct) {
    short8 bf[4];
#pragma unroll
    for (int kc = 0; kc < 4; ++kc)
      bf[kc] = *(const short8*)(cW1t_l + (ct * 16 + e16) * 128 + kc * 32 + q * 8);
    f32x4 acc[3] = {(f32x4){0,0,0,0}, (f32x4){0,0,0,0}, (f32x4){0,0,0,0}};
#pragma unroll
    for (int kc = 0; kc < 4; ++kc) {
#pragma unroll
      for (int grp = 0; grp < 3; ++grp)
        acc[grp] = __builtin_amdgcn_mfma_f32_16x16x32_bf16(af2[grp][kc], bf[kc], acc[grp], 0, 0, 0);
    }
    float cb = cb1_l[ct * 16 + e16];
    float c2 = cW2_l[ct * 16 + e16];
#pragma unroll
    for (int grp = 0; grp < 3; ++grp)
#pragma unroll
      for (int r = 0; r < 4; ++r)
        gp[grp][r] += silu_f(acc[grp][r] + cb) * c2;
  }
#pragma unroll
  for (int grp = 0; grp < 3; ++grp)
#pragma unroll
    for (int r = 0; r < 4; ++r) {
      float v = gp[grp][r];
      v += __shfl_xor(v, 1);
      v += __shfl_xor(v, 2);
      v += __shfl_xor(v, 4);
      v += __shfl_xor(v, 8);
      if (e16 == 0) sgate[grp * 16 + q * 4 + r] = v;
    }
  __syncthreads();  // ordering

  // m_i: node = q, col-chunk = e16*8 (bf16 out)
  {
    int nl = q, c8 = e16 * 8;
    float s[8] = {0,0,0,0,0,0,0,0};
#pragma unroll
    for (int r = 0; r < 12; ++r) {
      uint4 u = *(const uint4*)&mbuf[(nl * 12 + r) * 136 + c8];
      s[0] += blo(u.x); s[1] += bhi(u.x);
      s[2] += blo(u.y); s[3] += bhi(u.y);
      s[4] += blo(u.z); s[5] += bhi(u.z);
      s[6] += blo(u.w); s[7] += bhi(u.w);
    }
    uint4 o;
    o.x = pack2bf(s[0], s[1]); o.y = pack2bf(s[2], s[3]);
    o.z = pack2bf(s[4], s[5]); o.w = pack2bf(s[6], s[7]);
    *(uint4*)(m_i + (nbase + nl) * 128 + c8) = o;
  }
  // shift
  if (l6 < 12) {
    int nl = l6 / 3, c = l6 - nl * 3;
    float s = 0.f;
#pragma unroll
    for (int r = 0; r < 12; ++r) {
      int e = nl * 12 + r;
      s = fmaf(sdir[e * 4 + c], sgate[e], s);
    }
    int n = nbase + nl;
    if (addflag) shift_out[n * 3 + c] += s;
    else         shift_out[n * 3 + c] = s;
  }
}

// ---------------------------------------------------------------------------
// Fused node MLP, 4 cooperating waves over 16 rows (output-tile split):
// wave w does mt in {2w,2w+1} of GEMM-a/b and 4 of 16 hAB tiles.
// 4x wave parallelism vs 1-wave version; per-wave VMEM / dependency chain /4.
// ---------------------------------------------------------------------------
__global__ __launch_bounds__(256) void node_mfma(
    float* __restrict__ h, const unsigned short* __restrict__ m_i,
    const unsigned short* __restrict__ nW1t_l, const unsigned short* __restrict__ nW2t_l,
    const float* __restrict__ nb2_l, const float* __restrict__ tN_l,
    const unsigned short* __restrict__ eABt_next, unsigned short* __restrict__ hAB,
    int has_c)
{
  __shared__ unsigned short z1buf[16 * 136];
  __shared__ unsigned short hbuf[16 * 136];
  int tid = threadIdx.x;
  int wv = tid >> 6, l6 = tid & 63;
  int e16 = l6 & 15, q = l6 >> 4;
  int row = blockIdx.x * 16 + e16;
  int g = row / NPER;

  // B-fragments from [h | m_i] (all waves need all 8 kc; rows shared -> L1 hot)
  short8 bfh[8];
#pragma unroll
  for (int kc = 0; kc < 8; ++kc) {
    int k0 = kc * 32 + q * 8;
    if (k0 < 128) {
      float4 f0 = *(const float4*)(h + row * 128 + k0);
      float4 f1 = *(const float4*)(h + row * 128 + k0 + 4);
      float v[8] = {f0.x, f0.y, f0.z, f0.w, f1.x, f1.y, f1.z, f1.w};
      bfh[kc] = pack8(v);
    } else {
      bfh[kc] = *(const short8*)(m_i + row * 128 + (k0 - 128));
    }
  }
  // GEMM-a (transposed): z1^T = nW1^T @ [h|m_i]^T; wave w -> mt {2w,2w+1}
#pragma unroll
  for (int mi = 0; mi < 2; ++mi) {
    int mt = wv * 2 + mi;
    short8 af[8];
#pragma unroll
    for (int kc = 0; kc < 8; ++kc)
      af[kc] = *(const short8*)(nW1t_l + (mt * 16 + e16) * 256 + kc * 32 + q * 8);
    f32x4 acc = (f32x4){0,0,0,0};
#pragma unroll
    for (int kc = 0; kc < 8; ++kc)
      acc = __builtin_amdgcn_mfma_f32_16x16x32_bf16(af[kc], bfh[kc], acc, 0, 0, 0);
    float4 tv = *(const float4*)(tN_l + g * 128 + mt * 16 + q * 4);
    float v0 = silu_f(acc[0] + tv.x);
    float v1 = silu_f(acc[1] + tv.y);
    float v2 = silu_f(acc[2] + tv.z);
    float v3 = silu_f(acc[3] + tv.w);
    uint2 p; p.x = pack2bf(v0, v1); p.y = pack2bf(v2, v3);
    *(uint2*)&z1buf[e16 * 136 + mt * 16 + q * 4] = p;
  }
  __syncthreads();

  // GEMM-b (transposed): h_new^T = nW2^T @ z1^T (+h residual, +nb2)
  short8 zf[4];
#pragma unroll
  for (int kc = 0; kc < 4; ++kc)
    zf[kc] = *(const short8*)&z1buf[e16 * 136 + kc * 32 + q * 8];
#pragma unroll
  for (int mi = 0; mi < 2; ++mi) {
    int mt = wv * 2 + mi;
    short8 af[4];
#pragma unroll
    for (int kc = 0; kc < 4; ++kc)
      af[kc] = *(const short8*)(nW2t_l + (mt * 16 + e16) * 128 + kc * 32 + q * 8);
    f32x4 acc = (f32x4){0,0,0,0};
#pragma unroll
    for (int kc = 0; kc < 4; ++kc)
      acc = __builtin_amdgcn_mfma_f32_16x16x32_bf16(af[kc], zf[kc], acc, 0, 0, 0);
    float4 hv = *(const float4*)(h + row * 128 + mt * 16 + q * 4);
    float4 b4 = *(const float4*)(nb2_l + mt * 16 + q * 4);
    float4 o;
    o.x = hv.x + acc[0] + b4.x;
    o.y = hv.y + acc[1] + b4.y;
    o.z = hv.z + acc[2] + b4.z;
    o.w = hv.w + acc[3] + b4.w;
    *(float4*)(h + row * 128 + mt * 16 + q * 4) = o;
    uint2 p; p.x = pack2bf(o.x, o.y); p.y = pack2bf(o.z, o.w);
    *(uint2*)&hbuf[e16 * 136 + mt * 16 + q * 4] = p;
  }
  if (has_c) {
    __syncthreads();
    short8 hf[4];
#pragma unroll
    for (int kc = 0; kc < 4; ++kc)
      hf[kc] = *(const short8*)&hbuf[e16 * 136 + kc * 32 + q * 8];
#pragma unroll
    for (int mi = 0; mi < 4; ++mi) {
      int mt = wv * 4 + mi;
      short8 af[4];
#pragma unroll
      for (int kc = 0; kc < 4; ++kc)
        af[kc] = *(const short8*)(eABt_next + (mt * 16 + e16) * 128 + kc * 32 + q * 8);
      f32x4 acc = (f32x4){0,0,0,0};
#pragma unroll
      for (int kc = 0; kc < 4; ++kc)
        acc = __builtin_amdgcn_mfma_f32_16x16x32_bf16(af[kc], hf[kc], acc, 0, 0, 0);
      uint2 p; p.x = pack2bf(acc[0], acc[1]); p.y = pack2bf(acc[2], acc[3]);
      *(uint2*)(hAB + row * 256 + mt * 16 + q * 4) = p;
    }
  }
}

// ---------------------------------------------------------------------------
// Fused encoder, 4 cooperating waves over 16 rows (same split as node_mfma):
// h = [z|sp]@ne_W + ne_b; hAB = h@eABt[0]
// ---------------------------------------------------------------------------
__global__ __launch_bounds__(256) void encoder_mfma(
    const float* __restrict__ z, const int* __restrict__ species,
    const float* __restrict__ species_emb,
    const unsigned short* __restrict__ ne_Wt, const float* __restrict__ ne_b,
    const unsigned short* __restrict__ eABt0,
    float* __restrict__ h, unsigned short* __restrict__ hAB)
{
  __shared__ unsigned short hbuf[16 * 136];
  int tid = threadIdx.x;
  int wv = tid >> 6, l6 = tid & 63;
  int e16 = l6 & 15, q = l6 >> 4;
  int row = blockIdx.x * 16 + e16;
  int sp = species[row];
  sp = min(max(sp, 0), 118);

  short8 bfh[5];
#pragma unroll
  for (int kc = 0; kc < 5; ++kc) {
    int k0 = kc * 32 + q * 8;
    const float* src = (k0 < 128) ? (z + row * 128 + k0)
                                  : (species_emb + sp * 32 + (k0 - 128));
    float4 f0 = *(const float4*)src;
    float4 f1 = *(const float4*)(src + 4);
    float v[8] = {f0.x, f0.y, f0.z, f0.w, f1.x, f1.y, f1.z, f1.w};
    bfh[kc] = pack8(v);
  }
#pragma unroll
  for (int mi = 0; mi < 2; ++mi) {
    int mt = wv * 2 + mi;
    short8 af[5];
#pragma unroll
    for (int kc = 0; kc < 5; ++kc)
      af[kc] = *(const short8*)(ne_Wt + (mt * 16 + e16) * 160 + kc * 32 + q * 8);
    f32x4 acc = (f32x4){0,0,0,0};
#pragma unroll
    for (int kc = 0; kc < 5; ++kc)
      acc = __builtin_amdgcn_mfma_f32_16x16x32_bf16(af[kc], bfh[kc], acc, 0, 0, 0);
    float4 b4 = *(const float4*)(ne_b + mt * 16 + q * 4);
    float4 o;
    o.x = acc[0] + b4.x; o.y = acc[1] + b4.y;
    o.z = acc[2] + b4.z; o.w = acc[3] + b4.w;
    *(float4*)(h + row * 128 + mt * 16 + q * 4) = o;
    uint2 p; p.x = pack2bf(o.x, o.y); p.y = pack2bf(o.z, o.w);
    *(uint2*)&hbuf[e16 * 136 + mt * 16 + q * 4] = p;
  }
  __syncthreads();
  short8 hf[4];
#pragma unroll
  for (int kc = 0; kc < 4; ++kc)
    hf[kc] = *(const short8*)&hbuf[e16 * 136 + kc * 32 + q * 8];
#pragma unroll
  for (int mi = 0; mi < 4; ++mi) {
    int mt = wv * 4 + mi;
    short8 af[4];
#pragma unroll
    for (int kc = 0; kc < 4; ++kc)
      af[kc] = *(const short8*)(eABt0 + (mt * 16 + e16) * 128 + kc * 32 + q * 8);
    f32x4 acc = (f32x4){0,0,0,0};
#pragma unroll
    for (int kc = 0; kc < 4; ++kc)
      acc = __builtin_amdgcn_mfma_f32_16x16x32_bf16(af[kc], hf[kc], acc, 0, 0, 0);
    uint2 p; p.x = pack2bf(acc[0], acc[1]); p.y = pack2bf(acc[2], acc[3]);
    *(uint2*)(hAB + row * 256 + mt * 16 + q * 4) = p;
  }
}

extern "C" void kernel_launch(void* const* d_in, const int* in_sizes, int n_in,
                              void* d_out, int out_size, void* d_ws, size_t ws_size,
                              hipStream_t stream)
{
  const float* z_nodes     = (const float*)d_in[0];
  const float* t           = (const float*)d_in[1];
  const float* coords      = (const float*)d_in[2];
  const int*   species     = (const int*)d_in[3];
  const int*   edge_src    = (const int*)d_in[5];
  const float* species_emb = (const float*)d_in[7];
  const float* tm_W1 = (const float*)d_in[8];
  const float* tm_b1 = (const float*)d_in[9];
  const float* tm_W2 = (const float*)d_in[10];
  const float* tm_b2 = (const float*)d_in[11];
  const float* ne_W  = (const float*)d_in[12];
  const float* ne_b  = (const float*)d_in[13];
  const float* eW1   = (const float*)d_in[14];
  const float* eb1   = (const float*)d_in[15];
  const float* eW2   = (const float*)d_in[16];
  const float* eb2   = (const float*)d_in[17];
  const float* cW1   = (const float*)d_in[18];
  const float* cb1   = (const float*)d_in[19];
  const float* cW2   = (const float*)d_in[20];
  const float* nW1   = (const float*)d_in[21];
  const float* nb1   = (const float*)d_in[22];
  const float* nW2   = (const float*)d_in[23];
  const float* nb2   = (const float*)d_in[24];

  char* wsb = (char*)d_ws;
  float* temb = (float*)(wsb + 0);                          // 204800 B
  float* tEb  = (float*)(wsb + 204800);                     // 819200 B
  float* tNb  = (float*)(wsb + 1024000);                    // 819200 B
  unsigned short* hAB  = (unsigned short*)(wsb + 1843200);  // 10,240,000 B
  unsigned short* m_i  = (unsigned short*)(wsb + 12083200); // 5,120,000 B (bf16)
  unsigned short* eABt = (unsigned short*)(wsb + 17203200); // 262144
  unsigned short* eW2t = (unsigned short*)(wsb + 17465344); // 131072
  unsigned short* cW1t = (unsigned short*)(wsb + 17596416); // 131072
  unsigned short* nW1t = (unsigned short*)(wsb + 17727488); // 262144
  unsigned short* nW2t = (unsigned short*)(wsb + 17989632); // 131072
  unsigned short* ne_Wt= (unsigned short*)(wsb + 18120704); // 40960
  // total: 18,161,664 B

  float* outp  = (float*)d_out;
  float* shift = outp;            // [20000,3]
  float* h     = outp + 60000;    // [20000,128]

  time_kernel<<<GN, 128, 0, stream>>>(t, tm_W1, tm_b1, tm_W2, tm_b2,
                                      eW1, eb1, nW1, nb1, temb, tEb, tNb);
  prep_transpose<<<dim3(20, 29), 256, 0, stream>>>(eW1, eW2, cW1, nW1, nW2, ne_W,
                                                   eABt, eW2t, cW1t, nW1t, nW2t, ne_Wt);
  encoder_mfma<<<NN / 16, 256, 0, stream>>>(z_nodes, species, species_emb,
                                            ne_Wt, ne_b, eABt, h, hAB);
  for (int l = 0; l < LL; ++l) {
    edge_mfma<<<NN / 4, 64, 0, stream>>>(hAB, coords, edge_src, eW1,
                                         eW2t, eb2, cW1t, cb1, cW2, tEb,
                                         m_i, shift, l, (l > 0) ? 1 : 0);
    int has_c = (l < LL - 1) ? 1 : 0;
    node_mfma<<<NN / 16, 256, 0, stream>>>(h, m_i,
                                           nW1t + l * 128 * 256, nW2t + l * 16384,
                                           nb2 + l * 128, tNb + l * GN * 128,
                                           has_c ? (eABt + (l + 1) * 256 * 128) : eABt,
                                           hAB, has_c);
  }
}

// Round 8
// 570.192 us; speedup vs baseline: 1.0692x; 1.0060x over previous
//
#include <hip/hip_runtime.h>
#include <math.h>

#define GN 400
#define NPER 50
#define NN 20000
#define LL 4

typedef __attribute__((ext_vector_type(8))) short short8;
typedef __attribute__((ext_vector_type(4))) float f32x4;

__device__ __forceinline__ float fast_rcp(float x) {
#if __has_builtin(__builtin_amdgcn_rcpf)
  return __builtin_amdgcn_rcpf(x);
#else
  return 1.0f / x;
#endif
}
__device__ __forceinline__ float silu_f(float x) {
  return x * fast_rcp(1.0f + __expf(-x));
}
// Exact RNE (weights only)
__device__ __forceinline__ unsigned short f2bu(float f) {
  unsigned int u = __float_as_uint(f);
  unsigned int r = (u + 0x7fffu + ((u >> 16) & 1u)) >> 16;
  return (unsigned short)r;
}
// Fast round-half-up pack: 2 adds + 1 v_perm
__device__ __forceinline__ unsigned int pack2bf(float lo, float hi) {
  unsigned int a = __float_as_uint(lo) + 0x8000u;
  unsigned int b = __float_as_uint(hi) + 0x8000u;
#if __has_builtin(__builtin_amdgcn_perm)
  return __builtin_amdgcn_perm(b, a, 0x07060302);
#else
  return (b & 0xffff0000u) | (a >> 16);
#endif
}
__device__ __forceinline__ float bhi(unsigned int u) { return __uint_as_float(u & 0xffff0000u); }
__device__ __forceinline__ float blo(unsigned int u) { return __uint_as_float(u << 16); }

__device__ __forceinline__ short8 pack8(const float* v) {
  union { unsigned int u[4]; short8 s; } t;
  t.u[0] = pack2bf(v[0], v[1]);
  t.u[1] = pack2bf(v[2], v[3]);
  t.u[2] = pack2bf(v[4], v[5]);
  t.u[3] = pack2bf(v[6], v[7]);
  return t.s;
}
// Compiler-only ordering fence (no HW instruction): wave-private LDS RAW is
// in-order in HW; this just stops compiler reordering.
__device__ __forceinline__ void wave_fence() {
#if __has_builtin(__builtin_amdgcn_wave_barrier)
  __builtin_amdgcn_wave_barrier();
#else
  __syncthreads();
#endif
}

// ---------------------------------------------------------------------------
// Time embedding MLP + per-layer per-graph t-projections (400 graphs)
// ---------------------------------------------------------------------------
__global__ __launch_bounds__(128) void time_kernel(
    const float* __restrict__ t,
    const float* __restrict__ tm_W1, const float* __restrict__ tm_b1,
    const float* __restrict__ tm_W2, const float* __restrict__ tm_b2,
    const float* __restrict__ eW1, const float* __restrict__ eb1,
    const float* __restrict__ nW1, const float* __restrict__ nb1,
    float* __restrict__ temb, float* __restrict__ tE, float* __restrict__ tN)
{
  int g = blockIdx.x;
  int j = threadIdx.x;
  __shared__ float x[128];
  __shared__ float hid[256];
  __shared__ float te[128];
  float tv = t[g];
  if (j < 64) {
    float f = __expf((float)j * (-9.210340371976184f / 63.0f));
    float a = tv * f;
    x[j] = sinf(a);
    x[j + 64] = cosf(a);
  }
  __syncthreads();
  for (int o = j; o < 256; o += 128) {
    float acc = tm_b1[o];
    for (int k = 0; k < 128; ++k) acc = fmaf(x[k], tm_W1[k * 256 + o], acc);
    hid[o] = silu_f(acc);
  }
  __syncthreads();
  {
    float acc = tm_b2[j];
    for (int k = 0; k < 256; ++k) acc = fmaf(hid[k], tm_W2[k * 128 + j], acc);
    te[j] = acc;
    temb[g * 128 + j] = acc;
  }
  __syncthreads();
  for (int l = 0; l < LL; ++l) {
    const float* W = eW1 + (l * 385 + 257) * 128;
    float acc = eb1[l * 128 + j];
    for (int k = 0; k < 128; ++k) acc = fmaf(te[k], W[k * 128 + j], acc);
    tE[(l * GN + g) * 128 + j] = acc;
    const float* Wn = nW1 + (l * 384 + 256) * 128;
    float acc2 = nb1[l * 128 + j];
    for (int k = 0; k < 128; ++k) acc2 = fmaf(te[k], Wn[k * 128 + j], acc2);
    tN[(l * GN + g) * 128 + j] = acc2;
  }
}

// ---------------------------------------------------------------------------
// Weight prep: fp32 [K][128] -> bf16 transposed [n][k] (exact RNE).
// ---------------------------------------------------------------------------
__global__ __launch_bounds__(256) void prep_transpose(
    const float* __restrict__ eW1, const float* __restrict__ eW2,
    const float* __restrict__ cW1, const float* __restrict__ nW1,
    const float* __restrict__ nW2, const float* __restrict__ ne_W,
    unsigned short* __restrict__ eABt, unsigned short* __restrict__ eW2t,
    unsigned short* __restrict__ cW1t, unsigned short* __restrict__ nW1t,
    unsigned short* __restrict__ nW2t, unsigned short* __restrict__ ne_Wt)
{
  __shared__ float tile[32][33];
  int j = blockIdx.y;
  const float* src;
  unsigned short* dst;
  int dstride = 128, Kj = 128;
  if (j < 28) {
    int l = j / 7, m = j % 7;
    switch (m) {
      case 0: src = eW1 + (l * 385 + 0) * 128;   dst = eABt + l * 256 * 128;             break;
      case 1: src = eW1 + (l * 385 + 128) * 128; dst = eABt + l * 256 * 128 + 128 * 128; break;
      case 2: src = eW2 + l * 16384;             dst = eW2t + l * 16384;                 break;
      case 3: src = cW1 + l * 16384;             dst = cW1t + l * 16384;                 break;
      case 4: src = nW1 + (l * 384 + 0) * 128;   dst = nW1t + l * 128 * 256; dstride = 256; break;
      case 5: src = nW1 + (l * 384 + 128) * 128; dst = nW1t + l * 128 * 256 + 128; dstride = 256; break;
      default: src = nW2 + l * 16384;            dst = nW2t + l * 16384;                 break;
    }
  } else {
    src = ne_W; dst = ne_Wt; dstride = 160; Kj = 160;
  }
  int gx = blockIdx.x;
  int tk = (gx % 5) * 32;
  int tn = (gx / 5) * 32;
  if (tk >= Kj) return;
  int ti = threadIdx.x >> 5, tj = threadIdx.x & 31;
#pragma unroll
  for (int p = 0; p < 4; ++p) {
    int i = ti + p * 8;
    tile[i][tj] = src[(tk + i) * 128 + tn + tj];
  }
  __syncthreads();
#pragma unroll
  for (int p = 0; p < 4; ++p) {
    int i = ti + p * 8;
    dst[(tn + i) * dstride + tk + tj] = f2bu(tile[tj][i]);
  }
}

// ---------------------------------------------------------------------------
// Edge pipeline: 2 FULLY INDEPENDENT waves per block (round-4 per-wave code,
// wave-private LDS slices, ZERO barriers — LDS is in-order per wave; only a
// compiler scheduling fence at the two ordering points).
// ---------------------------------------------------------------------------
__global__ __launch_bounds__(128) void edge_mfma(
    const unsigned short* __restrict__ hAB,   // [NN][256] bf16
    const float* __restrict__ coords, const int* __restrict__ edge_src,
    const float* __restrict__ eW1,            // fp32 (dist_sq row)
    const unsigned short* __restrict__ eW2t, const float* __restrict__ eb2,
    const unsigned short* __restrict__ cW1t, const float* __restrict__ cb1,
    const float* __restrict__ cW2, const float* __restrict__ tE,
    unsigned short* __restrict__ m_i, float* __restrict__ shift_out,
    int l, int addflag)
{
  __shared__ unsigned short mbuf[2][48 * 136];
  __shared__ float sdir[2][48 * 4];
  __shared__ float sgate[2][48];

  int tid = threadIdx.x;
  int wv = tid >> 6;
  int l6 = tid & 63;
  int e16 = l6 & 15, q = l6 >> 4;
  int nbase = blockIdx.x * 8 + wv * 4;
  int ebase = nbase * 12;
  unsigned short* mb = mbuf[wv];
  float* sd = sdir[wv];
  float* sg = sgate[wv];

  const unsigned short* eW2t_l = eW2t + l * 16384;
  const unsigned short* cW1t_l = cW1t + l * 16384;
  const float* eb2_l = eb2 + l * 128;
  const float* cb1_l = cb1 + l * 128;
  const float* cW2_l = cW2 + l * 128;
  const float* tE_l = tE + l * GN * 128;
  const float* wd = eW1 + (l * 385 + 256) * 128;

  int ssrc[3], sdst[3];
  float sds[3];
#pragma unroll
  for (int grp = 0; grp < 3; ++grp) {
    int eloc = grp * 16 + e16;
    int e = ebase + eloc;
    int src = edge_src[e];
    src = min(max(src, 0), NN - 1);
    int dst = nbase + eloc / 12;
    float dx = coords[src * 3 + 0] - coords[dst * 3 + 0];
    float dy = coords[src * 3 + 1] - coords[dst * 3 + 1];
    float dz = coords[src * 3 + 2] - coords[dst * 3 + 2];
    float ds = dx * dx + dy * dy + dz * dz;
    float rinv = 1.0f / sqrtf(ds + 1e-8f);
    if (q == 0) {
      sd[eloc * 4 + 0] = dx * rinv;
      sd[eloc * 4 + 1] = dy * rinv;
      sd[eloc * 4 + 2] = dz * rinv;
    }
    ssrc[grp] = src; sdst[grp] = dst; sds[grp] = ds;
  }

  // Phase A: m1 B-fragments in registers
  short8 bfr[3][4];
#pragma unroll
  for (int grp = 0; grp < 3; ++grp) {
    int g = sdst[grp] / NPER;
    float ds = sds[grp];
#pragma unroll
    for (int kc = 0; kc < 4; ++kc) {
      int k0 = kc * 32 + q * 8;
      uint4 ua = *(const uint4*)(hAB + ssrc[grp] * 256 + k0);
      uint4 ub = *(const uint4*)(hAB + sdst[grp] * 256 + 128 + k0);
      float4 w0 = *(const float4*)(wd + k0);
      float4 w1 = *(const float4*)(wd + k0 + 4);
      float4 t0 = *(const float4*)(tE_l + g * 128 + k0);
      float4 t1 = *(const float4*)(tE_l + g * 128 + k0 + 4);
      float v[8];
      v[0] = silu_f(blo(ua.x) + blo(ub.x) + ds * w0.x + t0.x);
      v[1] = silu_f(bhi(ua.x) + bhi(ub.x) + ds * w0.y + t0.y);
      v[2] = silu_f(blo(ua.y) + blo(ub.y) + ds * w0.z + t0.z);
      v[3] = silu_f(bhi(ua.y) + bhi(ub.y) + ds * w0.w + t0.w);
      v[4] = silu_f(blo(ua.z) + blo(ub.z) + ds * w1.x + t1.x);
      v[5] = silu_f(bhi(ua.z) + bhi(ub.z) + ds * w1.y + t1.y);
      v[6] = silu_f(blo(ua.w) + blo(ub.w) + ds * w1.z + t1.z);
      v[7] = silu_f(bhi(ua.w) + bhi(ub.w) + ds * w1.w + t1.w);
      bfr[grp][kc] = pack8(v);
    }
  }

  // GEMM1 (transposed): m2^T = eW2^T @ m1^T -> packed b64 writes
#pragma unroll
  for (int mt = 0; mt < 8; ++mt) {
    short8 af[4];
#pragma unroll
    for (int kc = 0; kc < 4; ++kc)
      af[kc] = *(const short8*)(eW2t_l + (mt * 16 + e16) * 128 + kc * 32 + q * 8);
    f32x4 acc[3] = {(f32x4){0,0,0,0}, (f32x4){0,0,0,0}, (f32x4){0,0,0,0}};
#pragma unroll
    for (int kc = 0; kc < 4; ++kc) {
#pragma unroll
      for (int grp = 0; grp < 3; ++grp)
        acc[grp] = __builtin_amdgcn_mfma_f32_16x16x32_bf16(af[kc], bfr[grp][kc], acc[grp], 0, 0, 0);
    }
    float4 b4 = *(const float4*)(eb2_l + mt * 16 + q * 4);
#pragma unroll
    for (int grp = 0; grp < 3; ++grp) {
      float v0 = silu_f(acc[grp][0] + b4.x);
      float v1 = silu_f(acc[grp][1] + b4.y);
      float v2 = silu_f(acc[grp][2] + b4.z);
      float v3 = silu_f(acc[grp][3] + b4.w);
      uint2 p;
      p.x = pack2bf(v0, v1);
      p.y = pack2bf(v2, v3);
      *(uint2*)&mb[(grp * 16 + e16) * 136 + mt * 16 + q * 4] = p;
    }
  }
  wave_fence();  // compiler ordering only; HW LDS is in-order per wave

  // GEMM2: g = m2 @ cW1; gate = g . cW2
  short8 af2[3][4];
#pragma unroll
  for (int grp = 0; grp < 3; ++grp)
#pragma unroll
    for (int kc = 0; kc < 4; ++kc)
      af2[grp][kc] = *(const short8*)&mb[(grp * 16 + e16) * 136 + kc * 32 + q * 8];

  float gp[3][4] = {{0,0,0,0},{0,0,0,0},{0,0,0,0}};
#pragma unroll
  for (int ct = 0; ct < 8; ++ct) {
    short8 bf[4];
#pragma unroll
    for (int kc = 0; kc < 4; ++kc)
      bf[kc] = *(const short8*)(cW1t_l + (ct * 16 + e16) * 128 + kc * 32 + q * 8);
    f32x4 acc[3] = {(f32x4){0,0,0,0}, (f32x4){0,0,0,0}, (f32x4){0,0,0,0}};
#pragma unroll
    for (int kc = 0; kc < 4; ++kc) {
#pragma unroll
      for (int grp = 0; grp < 3; ++grp)
        acc[grp] = __builtin_amdgcn_mfma_f32_16x16x32_bf16(af2[grp][kc], bf[kc], acc[grp], 0, 0, 0);
    }
    float cb = cb1_l[ct * 16 + e16];
    float c2 = cW2_l[ct * 16 + e16];
#pragma unroll
    for (int grp = 0; grp < 3; ++grp)
#pragma unroll
      for (int r = 0; r < 4; ++r)
        gp[grp][r] += silu_f(acc[grp][r] + cb) * c2;
  }
#pragma unroll
  for (int grp = 0; grp < 3; ++grp)
#pragma unroll
    for (int r = 0; r < 4; ++r) {
      float v = gp[grp][r];
      v += __shfl_xor(v, 1);
      v += __shfl_xor(v, 2);
      v += __shfl_xor(v, 4);
      v += __shfl_xor(v, 8);
      if (e16 == 0) sg[grp * 16 + q * 4 + r] = v;
    }
  wave_fence();  // compiler ordering only

  // m_i: node = q, col-chunk = e16*8 (bf16 out)
  {
    int nl = q, c8 = e16 * 8;
    float s[8] = {0,0,0,0,0,0,0,0};
#pragma unroll
    for (int r = 0; r < 12; ++r) {
      uint4 u = *(const uint4*)&mb[(nl * 12 + r) * 136 + c8];
      s[0] += blo(u.x); s[1] += bhi(u.x);
      s[2] += blo(u.y); s[3] += bhi(u.y);
      s[4] += blo(u.z); s[5] += bhi(u.z);
      s[6] += blo(u.w); s[7] += bhi(u.w);
    }
    uint4 o;
    o.x = pack2bf(s[0], s[1]); o.y = pack2bf(s[2], s[3]);
    o.z = pack2bf(s[4], s[5]); o.w = pack2bf(s[6], s[7]);
    *(uint4*)(m_i + (nbase + nl) * 128 + c8) = o;
  }
  // shift
  if (l6 < 12) {
    int nl = l6 / 3, c = l6 - nl * 3;
    float s = 0.f;
#pragma unroll
    for (int r = 0; r < 12; ++r) {
      int e = nl * 12 + r;
      s = fmaf(sd[e * 4 + c], sg[e], s);
    }
    int n = nbase + nl;
    if (addflag) shift_out[n * 3 + c] += s;
    else         shift_out[n * 3 + c] = s;
  }
}

// ---------------------------------------------------------------------------
// Fused node MLP: 2 INDEPENDENT waves per block, each wave = round-4 code on
// its own 16-row slice. Wave-private LDS, zero barriers.
// ---------------------------------------------------------------------------
__global__ __launch_bounds__(128) void node_mfma(
    float* __restrict__ h, const unsigned short* __restrict__ m_i,
    const unsigned short* __restrict__ nW1t_l, const unsigned short* __restrict__ nW2t_l,
    const float* __restrict__ nb2_l, const float* __restrict__ tN_l,
    const unsigned short* __restrict__ eABt_next, unsigned short* __restrict__ hAB,
    int has_c)
{
  __shared__ unsigned short z1buf[2][16 * 136];
  __shared__ unsigned short hbuf[2][16 * 136];
  int tid = threadIdx.x;
  int wv = tid >> 6, l6 = tid & 63;
  int e16 = l6 & 15, q = l6 >> 4;
  int row = blockIdx.x * 32 + wv * 16 + e16;
  int g = row / NPER;
  unsigned short* zb = z1buf[wv];
  unsigned short* hb = hbuf[wv];

  short8 bfh[8];
#pragma unroll
  for (int kc = 0; kc < 8; ++kc) {
    int k0 = kc * 32 + q * 8;
    if (k0 < 128) {
      float4 f0 = *(const float4*)(h + row * 128 + k0);
      float4 f1 = *(const float4*)(h + row * 128 + k0 + 4);
      float v[8] = {f0.x, f0.y, f0.z, f0.w, f1.x, f1.y, f1.z, f1.w};
      bfh[kc] = pack8(v);
    } else {
      bfh[kc] = *(const short8*)(m_i + row * 128 + (k0 - 128));
    }
  }
#pragma unroll
  for (int mt = 0; mt < 8; ++mt) {
    short8 af[8];
#pragma unroll
    for (int kc = 0; kc < 8; ++kc)
      af[kc] = *(const short8*)(nW1t_l + (mt * 16 + e16) * 256 + kc * 32 + q * 8);
    f32x4 acc = (f32x4){0,0,0,0};
#pragma unroll
    for (int kc = 0; kc < 8; ++kc)
      acc = __builtin_amdgcn_mfma_f32_16x16x32_bf16(af[kc], bfh[kc], acc, 0, 0, 0);
    float4 tv = *(const float4*)(tN_l + g * 128 + mt * 16 + q * 4);
    float v0 = silu_f(acc[0] + tv.x);
    float v1 = silu_f(acc[1] + tv.y);
    float v2 = silu_f(acc[2] + tv.z);
    float v3 = silu_f(acc[3] + tv.w);
    uint2 p; p.x = pack2bf(v0, v1); p.y = pack2bf(v2, v3);
    *(uint2*)&zb[e16 * 136 + mt * 16 + q * 4] = p;
  }
  wave_fence();

  short8 zf[4];
#pragma unroll
  for (int kc = 0; kc < 4; ++kc)
    zf[kc] = *(const short8*)&zb[e16 * 136 + kc * 32 + q * 8];
#pragma unroll
  for (int mt = 0; mt < 8; ++mt) {
    short8 af[4];
#pragma unroll
    for (int kc = 0; kc < 4; ++kc)
      af[kc] = *(const short8*)(nW2t_l + (mt * 16 + e16) * 128 + kc * 32 + q * 8);
    f32x4 acc = (f32x4){0,0,0,0};
#pragma unroll
    for (int kc = 0; kc < 4; ++kc)
      acc = __builtin_amdgcn_mfma_f32_16x16x32_bf16(af[kc], zf[kc], acc, 0, 0, 0);
    float4 hv = *(const float4*)(h + row * 128 + mt * 16 + q * 4);
    float4 b4 = *(const float4*)(nb2_l + mt * 16 + q * 4);
    float4 o;
    o.x = hv.x + acc[0] + b4.x;
    o.y = hv.y + acc[1] + b4.y;
    o.z = hv.z + acc[2] + b4.z;
    o.w = hv.w + acc[3] + b4.w;
    *(float4*)(h + row * 128 + mt * 16 + q * 4) = o;
    uint2 p; p.x = pack2bf(o.x, o.y); p.y = pack2bf(o.z, o.w);
    *(uint2*)&hb[e16 * 136 + mt * 16 + q * 4] = p;
  }
  if (has_c) {
    wave_fence();
    short8 hf[4];
#pragma unroll
    for (int kc = 0; kc < 4; ++kc)
      hf[kc] = *(const short8*)&hb[e16 * 136 + kc * 32 + q * 8];
#pragma unroll
    for (int mt = 0; mt < 16; ++mt) {
      short8 af[4];
#pragma unroll
      for (int kc = 0; kc < 4; ++kc)
        af[kc] = *(const short8*)(eABt_next + (mt * 16 + e16) * 128 + kc * 32 + q * 8);
      f32x4 acc = (f32x4){0,0,0,0};
#pragma unroll
      for (int kc = 0; kc < 4; ++kc)
        acc = __builtin_amdgcn_mfma_f32_16x16x32_bf16(af[kc], hf[kc], acc, 0, 0, 0);
      uint2 p; p.x = pack2bf(acc[0], acc[1]); p.y = pack2bf(acc[2], acc[3]);
      *(uint2*)(hAB + row * 256 + mt * 16 + q * 4) = p;
    }
  }
}

// ---------------------------------------------------------------------------
// Fused encoder: 2 INDEPENDENT waves per block, 16 rows each.
// ---------------------------------------------------------------------------
__global__ __launch_bounds__(128) void encoder_mfma(
    const float* __restrict__ z, const int* __restrict__ species,
    const float* __restrict__ species_emb,
    const unsigned short* __restrict__ ne_Wt, const float* __restrict__ ne_b,
    const unsigned short* __restrict__ eABt0,
    float* __restrict__ h, unsigned short* __restrict__ hAB)
{
  __shared__ unsigned short hbuf[2][16 * 136];
  int tid = threadIdx.x;
  int wv = tid >> 6, l6 = tid & 63;
  int e16 = l6 & 15, q = l6 >> 4;
  int row = blockIdx.x * 32 + wv * 16 + e16;
  unsigned short* hb = hbuf[wv];
  int sp = species[row];
  sp = min(max(sp, 0), 118);

  short8 bfh[5];
#pragma unroll
  for (int kc = 0; kc < 5; ++kc) {
    int k0 = kc * 32 + q * 8;
    const float* src = (k0 < 128) ? (z + row * 128 + k0)
                                  : (species_emb + sp * 32 + (k0 - 128));
    float4 f0 = *(const float4*)src;
    float4 f1 = *(const float4*)(src + 4);
    float v[8] = {f0.x, f0.y, f0.z, f0.w, f1.x, f1.y, f1.z, f1.w};
    bfh[kc] = pack8(v);
  }
#pragma unroll
  for (int mt = 0; mt < 8; ++mt) {
    short8 af[5];
#pragma unroll
    for (int kc = 0; kc < 5; ++kc)
      af[kc] = *(const short8*)(ne_Wt + (mt * 16 + e16) * 160 + kc * 32 + q * 8);
    f32x4 acc = (f32x4){0,0,0,0};
#pragma unroll
    for (int kc = 0; kc < 5; ++kc)
      acc = __builtin_amdgcn_mfma_f32_16x16x32_bf16(af[kc], bfh[kc], acc, 0, 0, 0);
    float4 b4 = *(const float4*)(ne_b + mt * 16 + q * 4);
    float4 o;
    o.x = acc[0] + b4.x; o.y = acc[1] + b4.y;
    o.z = acc[2] + b4.z; o.w = acc[3] + b4.w;
    *(float4*)(h + row * 128 + mt * 16 + q * 4) = o;
    uint2 p; p.x = pack2bf(o.x, o.y); p.y = pack2bf(o.z, o.w);
    *(uint2*)&hb[e16 * 136 + mt * 16 + q * 4] = p;
  }
  wave_fence();
  short8 hf[4];
#pragma unroll
  for (int kc = 0; kc < 4; ++kc)
    hf[kc] = *(const short8*)&hb[e16 * 136 + kc * 32 + q * 8];
#pragma unroll
  for (int mt = 0; mt < 16; ++mt) {
    short8 af[4];
#pragma unroll
    for (int kc = 0; kc < 4; ++kc)
      af[kc] = *(const short8*)(eABt0 + (mt * 16 + e16) * 128 + kc * 32 + q * 8);
    f32x4 acc = (f32x4){0,0,0,0};
#pragma unroll
    for (int kc = 0; kc < 4; ++kc)
      acc = __builtin_amdgcn_mfma_f32_16x16x32_bf16(af[kc], hf[kc], acc, 0, 0, 0);
    uint2 p; p.x = pack2bf(acc[0], acc[1]); p.y = pack2bf(acc[2], acc[3]);
    *(uint2*)(hAB + row * 256 + mt * 16 + q * 4) = p;
  }
}

extern "C" void kernel_launch(void* const* d_in, const int* in_sizes, int n_in,
                              void* d_out, int out_size, void* d_ws, size_t ws_size,
                              hipStream_t stream)
{
  const float* z_nodes     = (const float*)d_in[0];
  const float* t           = (const float*)d_in[1];
  const float* coords      = (const float*)d_in[2];
  const int*   species     = (const int*)d_in[3];
  const int*   edge_src    = (const int*)d_in[5];
  const float* species_emb = (const float*)d_in[7];
  const float* tm_W1 = (const float*)d_in[8];
  const float* tm_b1 = (const float*)d_in[9];
  const float* tm_W2 = (const float*)d_in[10];
  const float* tm_b2 = (const float*)d_in[11];
  const float* ne_W  = (const float*)d_in[12];
  const float* ne_b  = (const float*)d_in[13];
  const float* eW1   = (const float*)d_in[14];
  const float* eb1   = (const float*)d_in[15];
  const float* eW2   = (const float*)d_in[16];
  const float* eb2   = (const float*)d_in[17];
  const float* cW1   = (const float*)d_in[18];
  const float* cb1   = (const float*)d_in[19];
  const float* cW2   = (const float*)d_in[20];
  const float* nW1   = (const float*)d_in[21];
  const float* nb1   = (const float*)d_in[22];
  const float* nW2   = (const float*)d_in[23];
  const float* nb2   = (const float*)d_in[24];

  char* wsb = (char*)d_ws;
  float* temb = (float*)(wsb + 0);                          // 204800 B
  float* tEb  = (float*)(wsb + 204800);                     // 819200 B
  float* tNb  = (float*)(wsb + 1024000);                    // 819200 B
  unsigned short* hAB  = (unsigned short*)(wsb + 1843200);  // 10,240,000 B
  unsigned short* m_i  = (unsigned short*)(wsb + 12083200); // 5,120,000 B (bf16)
  unsigned short* eABt = (unsigned short*)(wsb + 17203200); // 262144
  unsigned short* eW2t = (unsigned short*)(wsb + 17465344); // 131072
  unsigned short* cW1t = (unsigned short*)(wsb + 17596416); // 131072
  unsigned short* nW1t = (unsigned short*)(wsb + 17727488); // 262144
  unsigned short* nW2t = (unsigned short*)(wsb + 17989632); // 131072
  unsigned short* ne_Wt= (unsigned short*)(wsb + 18120704); // 40960
  // total: 18,161,664 B

  float* outp  = (float*)d_out;
  float* shift = outp;            // [20000,3]
  float* h     = outp + 60000;    // [20000,128]

  time_kernel<<<GN, 128, 0, stream>>>(t, tm_W1, tm_b1, tm_W2, tm_b2,
                                      eW1, eb1, nW1, nb1, temb, tEb, tNb);
  prep_transpose<<<dim3(20, 29), 256, 0, stream>>>(eW1, eW2, cW1, nW1, nW2, ne_W,
                                                   eABt, eW2t, cW1t, nW1t, nW2t, ne_Wt);
  encoder_mfma<<<NN / 32, 128, 0, stream>>>(z_nodes, species, species_emb,
                                            ne_Wt, ne_b, eABt, h, hAB);
  for (int l = 0; l < LL; ++l) {
    edge_mfma<<<NN / 8, 128, 0, stream>>>(hAB, coords, edge_src, eW1,
                                          eW2t, eb2, cW1t, cb1, cW2, tEb,
                                          m_i, shift, l, (l > 0) ? 1 : 0);
    int has_c = (l < LL - 1) ? 1 : 0;
    node_mfma<<<NN / 32, 128, 0, stream>>>(h, m_i,
                                           nW1t + l * 128 * 256, nW2t + l * 16384,
                                           nb2 + l * 128, tNb + l * GN * 128,
                                           has_c ? (eABt + (l + 1) * 256 * 128) : eABt,
                                           hAB, has_c);
  }
}

// Round 9
// 532.106 us; speedup vs baseline: 1.1457x; 1.0716x over previous
//
#include <hip/hip_runtime.h>
#include <math.h>

#define GN 400
#define NPER 50
#define NN 20000
#define LL 4

typedef __attribute__((ext_vector_type(8))) short short8;
typedef __attribute__((ext_vector_type(4))) float f32x4;

__device__ __forceinline__ float fast_rcp(float x) {
#if __has_builtin(__builtin_amdgcn_rcpf)
  return __builtin_amdgcn_rcpf(x);
#else
  return 1.0f / x;
#endif
}
__device__ __forceinline__ float silu_f(float x) {
  return x * fast_rcp(1.0f + __expf(-x));
}
// Exact RNE
__device__ __forceinline__ unsigned short f2bu(float f) {
  unsigned int u = __float_as_uint(f);
  unsigned int r = (u + 0x7fffu + ((u >> 16) & 1u)) >> 16;
  return (unsigned short)r;
}
__device__ __forceinline__ unsigned int pack2bf(float lo, float hi) {  // RNE
  return (unsigned int)f2bu(lo) | ((unsigned int)f2bu(hi) << 16);
}
// Fast round-half-up pack: 2 adds + 1 v_perm (edge kernel only)
__device__ __forceinline__ unsigned int pack2bf_fast(float lo, float hi) {
  unsigned int a = __float_as_uint(lo) + 0x8000u;
  unsigned int b = __float_as_uint(hi) + 0x8000u;
#if __has_builtin(__builtin_amdgcn_perm)
  return __builtin_amdgcn_perm(b, a, 0x07060302);
#else
  return (b & 0xffff0000u) | (a >> 16);
#endif
}
__device__ __forceinline__ float bhi(unsigned int u) { return __uint_as_float(u & 0xffff0000u); }
__device__ __forceinline__ float blo(unsigned int u) { return __uint_as_float(u << 16); }

__device__ __forceinline__ short8 pack8(const float* v) {  // RNE
  union { unsigned int u[4]; short8 s; } t;
  t.u[0] = pack2bf(v[0], v[1]);
  t.u[1] = pack2bf(v[2], v[3]);
  t.u[2] = pack2bf(v[4], v[5]);
  t.u[3] = pack2bf(v[6], v[7]);
  return t.s;
}
__device__ __forceinline__ short8 pack8_fast(const float* v) {
  union { unsigned int u[4]; short8 s; } t;
  t.u[0] = pack2bf_fast(v[0], v[1]);
  t.u[1] = pack2bf_fast(v[2], v[3]);
  t.u[2] = pack2bf_fast(v[4], v[5]);
  t.u[3] = pack2bf_fast(v[6], v[7]);
  return t.s;
}

// ---------------------------------------------------------------------------
// Time embedding MLP + per-layer per-graph t-projections (400 graphs)
// ---------------------------------------------------------------------------
__global__ __launch_bounds__(128) void time_kernel(
    const float* __restrict__ t,
    const float* __restrict__ tm_W1, const float* __restrict__ tm_b1,
    const float* __restrict__ tm_W2, const float* __restrict__ tm_b2,
    const float* __restrict__ eW1, const float* __restrict__ eb1,
    const float* __restrict__ nW1, const float* __restrict__ nb1,
    float* __restrict__ temb, float* __restrict__ tE, float* __restrict__ tN)
{
  int g = blockIdx.x;
  int j = threadIdx.x;
  __shared__ float x[128];
  __shared__ float hid[256];
  __shared__ float te[128];
  float tv = t[g];
  if (j < 64) {
    float f = __expf((float)j * (-9.210340371976184f / 63.0f));
    float a = tv * f;
    x[j] = sinf(a);
    x[j + 64] = cosf(a);
  }
  __syncthreads();
  for (int o = j; o < 256; o += 128) {
    float acc = tm_b1[o];
    for (int k = 0; k < 128; ++k) acc = fmaf(x[k], tm_W1[k * 256 + o], acc);
    hid[o] = silu_f(acc);
  }
  __syncthreads();
  {
    float acc = tm_b2[j];
    for (int k = 0; k < 256; ++k) acc = fmaf(hid[k], tm_W2[k * 128 + j], acc);
    te[j] = acc;
    temb[g * 128 + j] = acc;
  }
  __syncthreads();
  for (int l = 0; l < LL; ++l) {
    const float* W = eW1 + (l * 385 + 257) * 128;
    float acc = eb1[l * 128 + j];
    for (int k = 0; k < 128; ++k) acc = fmaf(te[k], W[k * 128 + j], acc);
    tE[(l * GN + g) * 128 + j] = acc;
    const float* Wn = nW1 + (l * 384 + 256) * 128;
    float acc2 = nb1[l * 128 + j];
    for (int k = 0; k < 128; ++k) acc2 = fmaf(te[k], Wn[k * 128 + j], acc2);
    tN[(l * GN + g) * 128 + j] = acc2;
  }
}

// ---------------------------------------------------------------------------
// Weight prep: fp32 [K][128] -> bf16 transposed [n][k] (exact RNE).
// ---------------------------------------------------------------------------
__global__ __launch_bounds__(256) void prep_transpose(
    const float* __restrict__ eW1, const float* __restrict__ eW2,
    const float* __restrict__ cW1, const float* __restrict__ nW1,
    const float* __restrict__ nW2, const float* __restrict__ ne_W,
    unsigned short* __restrict__ eABt, unsigned short* __restrict__ eW2t,
    unsigned short* __restrict__ cW1t, unsigned short* __restrict__ nW1t,
    unsigned short* __restrict__ nW2t, unsigned short* __restrict__ ne_Wt)
{
  __shared__ float tile[32][33];
  int j = blockIdx.y;
  const float* src;
  unsigned short* dst;
  int dstride = 128, Kj = 128;
  if (j < 28) {
    int l = j / 7, m = j % 7;
    switch (m) {
      case 0: src = eW1 + (l * 385 + 0) * 128;   dst = eABt + l * 256 * 128;             break;
      case 1: src = eW1 + (l * 385 + 128) * 128; dst = eABt + l * 256 * 128 + 128 * 128; break;
      case 2: src = eW2 + l * 16384;             dst = eW2t + l * 16384;                 break;
      case 3: src = cW1 + l * 16384;             dst = cW1t + l * 16384;                 break;
      case 4: src = nW1 + (l * 384 + 0) * 128;   dst = nW1t + l * 128 * 256; dstride = 256; break;
      case 5: src = nW1 + (l * 384 + 128) * 128; dst = nW1t + l * 128 * 256 + 128; dstride = 256; break;
      default: src = nW2 + l * 16384;            dst = nW2t + l * 16384;                 break;
    }
  } else {
    src = ne_W; dst = ne_Wt; dstride = 160; Kj = 160;
  }
  int gx = blockIdx.x;
  int tk = (gx % 5) * 32;
  int tn = (gx / 5) * 32;
  if (tk >= Kj) return;
  int ti = threadIdx.x >> 5, tj = threadIdx.x & 31;
#pragma unroll
  for (int p = 0; p < 4; ++p) {
    int i = ti + p * 8;
    tile[i][tj] = src[(tk + i) * 128 + tn + tj];
  }
  __syncthreads();
#pragma unroll
  for (int p = 0; p < 4; ++p) {
    int i = ti + p * 8;
    dst[(tn + i) * dstride + tk + tj] = f2bu(tile[tj][i]);
  }
}

// ---------------------------------------------------------------------------
// Edge pipeline: round-4 structure (1 wave/block, 48 edges = 4 nodes).
// tE is pre-folded into hAB's B half (see node_mfma/encoder epilogue), so
// Phase A is silu(hA[src] + hB'[dst] + ds*wd) with wd hoisted per kc.
// ---------------------------------------------------------------------------
__global__ __launch_bounds__(64) void edge_mfma(
    const unsigned short* __restrict__ hAB,   // [NN][256] bf16 (B half pre-biased)
    const float* __restrict__ coords, const int* __restrict__ edge_src,
    const float* __restrict__ eW1,            // fp32 (dist_sq row)
    const unsigned short* __restrict__ eW2t, const float* __restrict__ eb2,
    const unsigned short* __restrict__ cW1t, const float* __restrict__ cb1,
    const float* __restrict__ cW2,
    unsigned short* __restrict__ m_i, float* __restrict__ shift_out,
    int l, int addflag)
{
  __shared__ unsigned short mbuf[48 * 136];
  __shared__ float sdir[48 * 4];
  __shared__ float sgate[48];

  int l6 = threadIdx.x;
  int e16 = l6 & 15, q = l6 >> 4;
  int nbase = blockIdx.x * 4;
  int ebase = blockIdx.x * 48;

  const unsigned short* eW2t_l = eW2t + l * 16384;
  const unsigned short* cW1t_l = cW1t + l * 16384;
  const float* eb2_l = eb2 + l * 128;
  const float* cb1_l = cb1 + l * 128;
  const float* cW2_l = cW2 + l * 128;
  const float* wd = eW1 + (l * 385 + 256) * 128;

  int ssrc[3], sdst[3];
  float sds[3];
#pragma unroll
  for (int grp = 0; grp < 3; ++grp) {
    int eloc = grp * 16 + e16;
    int e = ebase + eloc;
    int src = edge_src[e];
    src = min(max(src, 0), NN - 1);
    int dst = nbase + eloc / 12;
    float dx = coords[src * 3 + 0] - coords[dst * 3 + 0];
    float dy = coords[src * 3 + 1] - coords[dst * 3 + 1];
    float dz = coords[src * 3 + 2] - coords[dst * 3 + 2];
    float ds = dx * dx + dy * dy + dz * dz;
    float rinv = 1.0f / sqrtf(ds + 1e-8f);
    if (q == 0) {
      sdir[eloc * 4 + 0] = dx * rinv;
      sdir[eloc * 4 + 1] = dy * rinv;
      sdir[eloc * 4 + 2] = dz * rinv;
    }
    ssrc[grp] = src; sdst[grp] = dst; sds[grp] = ds;
  }

  // Phase A: m1 B-fragments; kc-outer so wd loads are shared across grps
  short8 bfr[3][4];
#pragma unroll
  for (int kc = 0; kc < 4; ++kc) {
    int k0 = kc * 32 + q * 8;
    float4 w0 = *(const float4*)(wd + k0);
    float4 w1 = *(const float4*)(wd + k0 + 4);
#pragma unroll
    for (int grp = 0; grp < 3; ++grp) {
      float ds = sds[grp];
      uint4 ua = *(const uint4*)(hAB + ssrc[grp] * 256 + k0);
      uint4 ub = *(const uint4*)(hAB + sdst[grp] * 256 + 128 + k0);
      float v[8];
      v[0] = silu_f(blo(ua.x) + blo(ub.x) + ds * w0.x);
      v[1] = silu_f(bhi(ua.x) + bhi(ub.x) + ds * w0.y);
      v[2] = silu_f(blo(ua.y) + blo(ub.y) + ds * w0.z);
      v[3] = silu_f(bhi(ua.y) + bhi(ub.y) + ds * w0.w);
      v[4] = silu_f(blo(ua.z) + blo(ub.z) + ds * w1.x);
      v[5] = silu_f(bhi(ua.z) + bhi(ub.z) + ds * w1.y);
      v[6] = silu_f(blo(ua.w) + blo(ub.w) + ds * w1.z);
      v[7] = silu_f(bhi(ua.w) + bhi(ub.w) + ds * w1.w);
      bfr[grp][kc] = pack8_fast(v);
    }
  }

  // GEMM1 (transposed): m2^T = eW2^T @ m1^T -> packed b64 writes
#pragma unroll
  for (int mt = 0; mt < 8; ++mt) {
    short8 af[4];
#pragma unroll
    for (int kc = 0; kc < 4; ++kc)
      af[kc] = *(const short8*)(eW2t_l + (mt * 16 + e16) * 128 + kc * 32 + q * 8);
    f32x4 acc[3] = {(f32x4){0,0,0,0}, (f32x4){0,0,0,0}, (f32x4){0,0,0,0}};
#pragma unroll
    for (int kc = 0; kc < 4; ++kc) {
#pragma unroll
      for (int grp = 0; grp < 3; ++grp)
        acc[grp] = __builtin_amdgcn_mfma_f32_16x16x32_bf16(af[kc], bfr[grp][kc], acc[grp], 0, 0, 0);
    }
    float4 b4 = *(const float4*)(eb2_l + mt * 16 + q * 4);
#pragma unroll
    for (int grp = 0; grp < 3; ++grp) {
      float v0 = silu_f(acc[grp][0] + b4.x);
      float v1 = silu_f(acc[grp][1] + b4.y);
      float v2 = silu_f(acc[grp][2] + b4.z);
      float v3 = silu_f(acc[grp][3] + b4.w);
      uint2 p;
      p.x = pack2bf_fast(v0, v1);
      p.y = pack2bf_fast(v2, v3);
      *(uint2*)&mbuf[(grp * 16 + e16) * 136 + mt * 16 + q * 4] = p;
    }
  }
  __syncthreads();  // single wave: waitcnt only

  // GEMM2: g = m2 @ cW1; gate = g . cW2
  short8 af2[3][4];
#pragma unroll
  for (int grp = 0; grp < 3; ++grp)
#pragma unroll
    for (int kc = 0; kc < 4; ++kc)
      af2[grp][kc] = *(const short8*)&mbuf[(grp * 16 + e16) * 136 + kc * 32 + q * 8];

  float gp[3][4] = {{0,0,0,0},{0,0,0,0},{0,0,0,0}};
#pragma unroll
  for (int ct = 0; ct < 8; ++ct) {
    short8 bf[4];
#pragma unroll
    for (int kc = 0; kc < 4; ++kc)
      bf[kc] = *(const short8*)(cW1t_l + (ct * 16 + e16) * 128 + kc * 32 + q * 8);
    f32x4 acc[3] = {(f32x4){0,0,0,0}, (f32x4){0,0,0,0}, (f32x4){0,0,0,0}};
#pragma unroll
    for (int kc = 0; kc < 4; ++kc) {
#pragma unroll
      for (int grp = 0; grp < 3; ++grp)
        acc[grp] = __builtin_amdgcn_mfma_f32_16x16x32_bf16(af2[grp][kc], bf[kc], acc[grp], 0, 0, 0);
    }
    float cb = cb1_l[ct * 16 + e16];
    float c2 = cW2_l[ct * 16 + e16];
#pragma unroll
    for (int grp = 0; grp < 3; ++grp)
#pragma unroll
      for (int r = 0; r < 4; ++r)
        gp[grp][r] += silu_f(acc[grp][r] + cb) * c2;
  }
#pragma unroll
  for (int grp = 0; grp < 3; ++grp)
#pragma unroll
    for (int r = 0; r < 4; ++r) {
      float v = gp[grp][r];
      v += __shfl_xor(v, 1);
      v += __shfl_xor(v, 2);
      v += __shfl_xor(v, 4);
      v += __shfl_xor(v, 8);
      if (e16 == 0) sgate[grp * 16 + q * 4 + r] = v;
    }
  __syncthreads();  // ordering

  // m_i: node = q, col-chunk = e16*8 (bf16 out)
  {
    int nl = q, c8 = e16 * 8;
    float s[8] = {0,0,0,0,0,0,0,0};
#pragma unroll
    for (int r = 0; r < 12; ++r) {
      uint4 u = *(const uint4*)&mbuf[(nl * 12 + r) * 136 + c8];
      s[0] += blo(u.x); s[1] += bhi(u.x);
      s[2] += blo(u.y); s[3] += bhi(u.y);
      s[4] += blo(u.z); s[5] += bhi(u.z);
      s[6] += blo(u.w); s[7] += bhi(u.w);
    }
    uint4 o;
    o.x = pack2bf_fast(s[0], s[1]); o.y = pack2bf_fast(s[2], s[3]);
    o.z = pack2bf_fast(s[4], s[5]); o.w = pack2bf_fast(s[6], s[7]);
    *(uint4*)(m_i + (nbase + nl) * 128 + c8) = o;
  }
  // shift
  if (l6 < 12) {
    int nl = l6 / 3, c = l6 - nl * 3;
    float s = 0.f;
#pragma unroll
    for (int r = 0; r < 12; ++r) {
      int e = nl * 12 + r;
      s = fmaf(sdir[e * 4 + c], sgate[e], s);
    }
    int n = nbase + nl;
    if (addflag) shift_out[n * 3 + c] += s;
    else         shift_out[n * 3 + c] = s;
  }
}

// ---------------------------------------------------------------------------
// Fused node MLP (round-4 shape, 1 wave, 16 rows):
// h += silu([h|m_i]@nW1 + tN) @ nW2 + nb2; then (optional) hAB = h @ eABt_next
// with tE_next[g] folded into the B half of hAB.
// ---------------------------------------------------------------------------
__global__ __launch_bounds__(64) void node_mfma(
    float* __restrict__ h, const unsigned short* __restrict__ m_i,
    const unsigned short* __restrict__ nW1t_l, const unsigned short* __restrict__ nW2t_l,
    const float* __restrict__ nb2_l, const float* __restrict__ tN_l,
    const unsigned short* __restrict__ eABt_next, const float* __restrict__ tE_next,
    unsigned short* __restrict__ hAB, int has_c)
{
  __shared__ unsigned short z1buf[16 * 136];
  __shared__ unsigned short hbuf[16 * 136];
  int l6 = threadIdx.x, e16 = l6 & 15, q = l6 >> 4;
  int row = blockIdx.x * 16 + e16;
  int g = row / NPER;

  short8 bfh[8];
#pragma unroll
  for (int kc = 0; kc < 8; ++kc) {
    int k0 = kc * 32 + q * 8;
    if (k0 < 128) {
      float4 f0 = *(const float4*)(h + row * 128 + k0);
      float4 f1 = *(const float4*)(h + row * 128 + k0 + 4);
      float v[8] = {f0.x, f0.y, f0.z, f0.w, f1.x, f1.y, f1.z, f1.w};
      bfh[kc] = pack8(v);
    } else {
      bfh[kc] = *(const short8*)(m_i + row * 128 + (k0 - 128));
    }
  }
#pragma unroll
  for (int mt = 0; mt < 8; ++mt) {
    short8 af[8];
#pragma unroll
    for (int kc = 0; kc < 8; ++kc)
      af[kc] = *(const short8*)(nW1t_l + (mt * 16 + e16) * 256 + kc * 32 + q * 8);
    f32x4 acc = (f32x4){0,0,0,0};
#pragma unroll
    for (int kc = 0; kc < 8; ++kc)
      acc = __builtin_amdgcn_mfma_f32_16x16x32_bf16(af[kc], bfh[kc], acc, 0, 0, 0);
    float4 tv = *(const float4*)(tN_l + g * 128 + mt * 16 + q * 4);
    float v0 = silu_f(acc[0] + tv.x);
    float v1 = silu_f(acc[1] + tv.y);
    float v2 = silu_f(acc[2] + tv.z);
    float v3 = silu_f(acc[3] + tv.w);
    uint2 p; p.x = pack2bf(v0, v1); p.y = pack2bf(v2, v3);
    *(uint2*)&z1buf[e16 * 136 + mt * 16 + q * 4] = p;
  }
  __syncthreads();

  short8 zf[4];
#pragma unroll
  for (int kc = 0; kc < 4; ++kc)
    zf[kc] = *(const short8*)&z1buf[e16 * 136 + kc * 32 + q * 8];
#pragma unroll
  for (int mt = 0; mt < 8; ++mt) {
    short8 af[4];
#pragma unroll
    for (int kc = 0; kc < 4; ++kc)
      af[kc] = *(const short8*)(nW2t_l + (mt * 16 + e16) * 128 + kc * 32 + q * 8);
    f32x4 acc = (f32x4){0,0,0,0};
#pragma unroll
    for (int kc = 0; kc < 4; ++kc)
      acc = __builtin_amdgcn_mfma_f32_16x16x32_bf16(af[kc], zf[kc], acc, 0, 0, 0);
    float4 hv = *(const float4*)(h + row * 128 + mt * 16 + q * 4);
    float4 b4 = *(const float4*)(nb2_l + mt * 16 + q * 4);
    float4 o;
    o.x = hv.x + acc[0] + b4.x;
    o.y = hv.y + acc[1] + b4.y;
    o.z = hv.z + acc[2] + b4.z;
    o.w = hv.w + acc[3] + b4.w;
    *(float4*)(h + row * 128 + mt * 16 + q * 4) = o;
    uint2 p; p.x = pack2bf(o.x, o.y); p.y = pack2bf(o.z, o.w);
    *(uint2*)&hbuf[e16 * 136 + mt * 16 + q * 4] = p;
  }
  if (has_c) {
    __syncthreads();
    short8 hf[4];
#pragma unroll
    for (int kc = 0; kc < 4; ++kc)
      hf[kc] = *(const short8*)&hbuf[e16 * 136 + kc * 32 + q * 8];
#pragma unroll
    for (int mt = 0; mt < 16; ++mt) {
      short8 af[4];
#pragma unroll
      for (int kc = 0; kc < 4; ++kc)
        af[kc] = *(const short8*)(eABt_next + (mt * 16 + e16) * 128 + kc * 32 + q * 8);
      f32x4 acc = (f32x4){0,0,0,0};
#pragma unroll
      for (int kc = 0; kc < 4; ++kc)
        acc = __builtin_amdgcn_mfma_f32_16x16x32_bf16(af[kc], hf[kc], acc, 0, 0, 0);
      if (mt >= 8) {   // B half: fold tE_next[g]
        float4 tv = *(const float4*)(tE_next + g * 128 + (mt - 8) * 16 + q * 4);
        acc[0] += tv.x; acc[1] += tv.y; acc[2] += tv.z; acc[3] += tv.w;
      }
      uint2 p; p.x = pack2bf(acc[0], acc[1]); p.y = pack2bf(acc[2], acc[3]);
      *(uint2*)(hAB + row * 256 + mt * 16 + q * 4) = p;
    }
  }
}

// ---------------------------------------------------------------------------
// Fused encoder (round-4 shape): h = [z|sp]@ne_W + ne_b; hAB = h@eABt[0]
// with tE[0][g] folded into the B half.
// ---------------------------------------------------------------------------
__global__ __launch_bounds__(64) void encoder_mfma(
    const float* __restrict__ z, const int* __restrict__ species,
    const float* __restrict__ species_emb,
    const unsigned short* __restrict__ ne_Wt, const float* __restrict__ ne_b,
    const unsigned short* __restrict__ eABt0, const float* __restrict__ tE0,
    float* __restrict__ h, unsigned short* __restrict__ hAB)
{
  __shared__ unsigned short hbuf[16 * 136];
  int l6 = threadIdx.x, e16 = l6 & 15, q = l6 >> 4;
  int row = blockIdx.x * 16 + e16;
  int g = row / NPER;
  int sp = species[row];
  sp = min(max(sp, 0), 118);

  short8 bfh[5];
#pragma unroll
  for (int kc = 0; kc < 5; ++kc) {
    int k0 = kc * 32 + q * 8;
    const float* src = (k0 < 128) ? (z + row * 128 + k0)
                                  : (species_emb + sp * 32 + (k0 - 128));
    float4 f0 = *(const float4*)src;
    float4 f1 = *(const float4*)(src + 4);
    float v[8] = {f0.x, f0.y, f0.z, f0.w, f1.x, f1.y, f1.z, f1.w};
    bfh[kc] = pack8(v);
  }
#pragma unroll
  for (int mt = 0; mt < 8; ++mt) {
    short8 af[5];
#pragma unroll
    for (int kc = 0; kc < 5; ++kc)
      af[kc] = *(const short8*)(ne_Wt + (mt * 16 + e16) * 160 + kc * 32 + q * 8);
    f32x4 acc = (f32x4){0,0,0,0};
#pragma unroll
    for (int kc = 0; kc < 5; ++kc)
      acc = __builtin_amdgcn_mfma_f32_16x16x32_bf16(af[kc], bfh[kc], acc, 0, 0, 0);
    float4 b4 = *(const float4*)(ne_b + mt * 16 + q * 4);
    float4 o;
    o.x = acc[0] + b4.x; o.y = acc[1] + b4.y;
    o.z = acc[2] + b4.z; o.w = acc[3] + b4.w;
    *(float4*)(h + row * 128 + mt * 16 + q * 4) = o;
    uint2 p; p.x = pack2bf(o.x, o.y); p.y = pack2bf(o.z, o.w);
    *(uint2*)&hbuf[e16 * 136 + mt * 16 + q * 4] = p;
  }
  __syncthreads();
  short8 hf[4];
#pragma unroll
  for (int kc = 0; kc < 4; ++kc)
    hf[kc] = *(const short8*)&hbuf[e16 * 136 + kc * 32 + q * 8];
#pragma unroll
  for (int mt = 0; mt < 16; ++mt) {
    short8 af[4];
#pragma unroll
    for (int kc = 0; kc < 4; ++kc)
      af[kc] = *(const short8*)(eABt0 + (mt * 16 + e16) * 128 + kc * 32 + q * 8);
    f32x4 acc = (f32x4){0,0,0,0};
#pragma unroll
    for (int kc = 0; kc < 4; ++kc)
      acc = __builtin_amdgcn_mfma_f32_16x16x32_bf16(af[kc], hf[kc], acc, 0, 0, 0);
    if (mt >= 8) {   // B half: fold tE0[g]
      float4 tv = *(const float4*)(tE0 + g * 128 + (mt - 8) * 16 + q * 4);
      acc[0] += tv.x; acc[1] += tv.y; acc[2] += tv.z; acc[3] += tv.w;
    }
    uint2 p; p.x = pack2bf(acc[0], acc[1]); p.y = pack2bf(acc[2], acc[3]);
    *(uint2*)(hAB + row * 256 + mt * 16 + q * 4) = p;
  }
}

extern "C" void kernel_launch(void* const* d_in, const int* in_sizes, int n_in,
                              void* d_out, int out_size, void* d_ws, size_t ws_size,
                              hipStream_t stream)
{
  const float* z_nodes     = (const float*)d_in[0];
  const float* t           = (const float*)d_in[1];
  const float* coords      = (const float*)d_in[2];
  const int*   species     = (const int*)d_in[3];
  const int*   edge_src    = (const int*)d_in[5];
  const float* species_emb = (const float*)d_in[7];
  const float* tm_W1 = (const float*)d_in[8];
  const float* tm_b1 = (const float*)d_in[9];
  const float* tm_W2 = (const float*)d_in[10];
  const float* tm_b2 = (const float*)d_in[11];
  const float* ne_W  = (const float*)d_in[12];
  const float* ne_b  = (const float*)d_in[13];
  const float* eW1   = (const float*)d_in[14];
  const float* eb1   = (const float*)d_in[15];
  const float* eW2   = (const float*)d_in[16];
  const float* eb2   = (const float*)d_in[17];
  const float* cW1   = (const float*)d_in[18];
  const float* cb1   = (const float*)d_in[19];
  const float* cW2   = (const float*)d_in[20];
  const float* nW1   = (const float*)d_in[21];
  const float* nb1   = (const float*)d_in[22];
  const float* nW2   = (const float*)d_in[23];
  const float* nb2   = (const float*)d_in[24];

  char* wsb = (char*)d_ws;
  float* temb = (float*)(wsb + 0);                          // 204800 B
  float* tEb  = (float*)(wsb + 204800);                     // 819200 B
  float* tNb  = (float*)(wsb + 1024000);                    // 819200 B
  unsigned short* hAB  = (unsigned short*)(wsb + 1843200);  // 10,240,000 B
  unsigned short* m_i  = (unsigned short*)(wsb + 12083200); // 5,120,000 B (bf16)
  unsigned short* eABt = (unsigned short*)(wsb + 17203200); // 262144
  unsigned short* eW2t = (unsigned short*)(wsb + 17465344); // 131072
  unsigned short* cW1t = (unsigned short*)(wsb + 17596416); // 131072
  unsigned short* nW1t = (unsigned short*)(wsb + 17727488); // 262144
  unsigned short* nW2t = (unsigned short*)(wsb + 17989632); // 131072
  unsigned short* ne_Wt= (unsigned short*)(wsb + 18120704); // 40960
  // total: 18,161,664 B

  float* outp  = (float*)d_out;
  float* shift = outp;            // [20000,3]
  float* h     = outp + 60000;    // [20000,128]

  time_kernel<<<GN, 128, 0, stream>>>(t, tm_W1, tm_b1, tm_W2, tm_b2,
                                      eW1, eb1, nW1, nb1, temb, tEb, tNb);
  prep_transpose<<<dim3(20, 29), 256, 0, stream>>>(eW1, eW2, cW1, nW1, nW2, ne_W,
                                                   eABt, eW2t, cW1t, nW1t, nW2t, ne_Wt);
  encoder_mfma<<<NN / 16, 64, 0, stream>>>(z_nodes, species, species_emb,
                                           ne_Wt, ne_b, eABt, tEb, h, hAB);
  for (int l = 0; l < LL; ++l) {
    edge_mfma<<<NN / 4, 64, 0, stream>>>(hAB, coords, edge_src, eW1,
                                         eW2t, eb2, cW1t, cb1, cW2,
                                         m_i, shift, l, (l > 0) ? 1 : 0);
    int has_c = (l < LL - 1) ? 1 : 0;
    node_mfma<<<NN / 16, 64, 0, stream>>>(h, m_i,
                                          nW1t + l * 128 * 256, nW2t + l * 16384,
                                          nb2 + l * 128, tNb + l * GN * 128,
                                          has_c ? (eABt + (l + 1) * 256 * 128) : eABt,
                                          has_c ? (tEb + (l + 1) * GN * 128) : tEb,
                                          hAB, has_c);
  }
}